// Round 1
// baseline (1748.629 us; speedup 1.0000x reference)
//
#include <hip/hip_runtime.h>

// GPT2-like forward, MI355X. Round 0: correctness-first bf16-MFMA pipeline.
// - residual stream x: f32
// - all matmuls: bf16 MFMA 16x16x32, f32 accum
// - weights converted f32->bf16 and transposed to [N][K] per-GEMM (k_wtrans)
// - flash attention, online softmax in f32

#define T_SEQ 1024
#define NTOK  2048   // B*T
#define DM    1024
#define DFF   4096
#define NH    16
#define DH    64
#define NL    6
#define VOCAB 32000

typedef short sx8 __attribute__((ext_vector_type(8)));          // 8 bf16 (4 VGPR) MFMA frag
typedef float fx4 __attribute__((ext_vector_type(4)));          // MFMA acc
typedef unsigned short usx4 __attribute__((ext_vector_type(4)));
typedef unsigned short usx8 __attribute__((ext_vector_type(8)));
typedef unsigned int   uix4 __attribute__((ext_vector_type(4))); // 16B copy

__device__ __forceinline__ unsigned short f2bf(float f) {
  union { float f; unsigned u; } c; c.f = f;
  unsigned r = c.u + 0x7FFFu + ((c.u >> 16) & 1u);   // round-nearest-even
  return (unsigned short)(r >> 16);
}

// ---------------- embedding: x = tok_emb[idx] + pos_emb ----------------
__global__ __launch_bounds__(256) void k_embed(const int* __restrict__ idx,
                                               const float* __restrict__ tok,
                                               const float* __restrict__ pos,
                                               float* __restrict__ x) {
  int token = blockIdx.x;
  int t = token & (T_SEQ - 1);
  int id = idx[token];
  int c = threadIdx.x * 4;
  float4 tv = *(const float4*)&tok[(size_t)id * DM + c];
  float4 pv = *(const float4*)&pos[(size_t)t * DM + c];
  float4 r;
  r.x = tv.x + pv.x; r.y = tv.y + pv.y; r.z = tv.z + pv.z; r.w = tv.w + pv.w;
  *(float4*)&x[(size_t)token * DM + c] = r;
}

// ---------------- layernorm: h(bf16) = LN(x)*g + b ----------------
__global__ __launch_bounds__(256) void k_ln(const float* __restrict__ x,
                                            const float* __restrict__ g,
                                            const float* __restrict__ b,
                                            unsigned short* __restrict__ h) {
  int row = blockIdx.x;
  int tid = threadIdx.x;
  float4 v = *(const float4*)&x[(size_t)row * DM + tid * 4];
  float s = v.x + v.y + v.z + v.w;
  float q = v.x * v.x + v.y * v.y + v.z * v.z + v.w * v.w;
  for (int off = 32; off > 0; off >>= 1) {
    s += __shfl_down(s, off);
    q += __shfl_down(q, off);
  }
  __shared__ float red[8];
  int wid = tid >> 6, lane = tid & 63;
  if (lane == 0) { red[wid] = s; red[4 + wid] = q; }
  __syncthreads();
  s = red[0] + red[1] + red[2] + red[3];
  q = red[4] + red[5] + red[6] + red[7];
  float mu = s * (1.0f / DM);
  float var = q * (1.0f / DM) - mu * mu;
  float rstd = rsqrtf(var + 1e-5f);
  float4 gg = *(const float4*)&g[tid * 4];
  float4 bb = *(const float4*)&b[tid * 4];
  usx4 o;
  o[0] = f2bf((v.x - mu) * rstd * gg.x + bb.x);
  o[1] = f2bf((v.y - mu) * rstd * gg.y + bb.y);
  o[2] = f2bf((v.z - mu) * rstd * gg.z + bb.z);
  o[3] = f2bf((v.w - mu) * rstd * gg.w + bb.w);
  *(usx4*)&h[(size_t)row * DM + tid * 4] = o;
}

// ---------------- weight convert+transpose: WT[n][k] = bf16(W[k][n]) ----------------
__global__ __launch_bounds__(256) void k_wtrans(const float* __restrict__ W,
                                                unsigned short* __restrict__ WT,
                                                int K, int N) {
  __shared__ float t[64][68];
  int k0 = blockIdx.x * 64, n0 = blockIdx.y * 64;
  int tid = threadIdx.x;
#pragma unroll
  for (int i = 0; i < 4; ++i) {
    int chunk = i * 256 + tid;
    int r = chunk >> 4, c = (chunk & 15) << 2;
    float4 v = *(const float4*)&W[(size_t)(k0 + r) * N + n0 + c];
    t[r][c] = v.x; t[r][c + 1] = v.y; t[r][c + 2] = v.z; t[r][c + 3] = v.w;
  }
  __syncthreads();
#pragma unroll
  for (int i = 0; i < 4; ++i) {
    int chunk = i * 256 + tid;
    int n = chunk >> 4, c = (chunk & 15) << 2;
    usx4 o;
    o[0] = f2bf(t[c][n]);
    o[1] = f2bf(t[c + 1][n]);
    o[2] = f2bf(t[c + 2][n]);
    o[3] = f2bf(t[c + 3][n]);
    *(usx4*)&WT[(size_t)(n0 + n) * K + k0 + c] = o;
  }
}

// ---------------- GEMM: C[M=2048,N] = A[M,K](bf16) * BT[N,K]^T(bf16) ----------------
// 128x128 tile, BK=64, 4 waves (2x2), each wave 64x64 out via 4x4 mfma_16x16x32.
// LDS rows padded to 72 elems (144B, 16B-aligned) to spread ds_read_b128 banks.
// EPI: 0=qkv scatter(+bias), 1=gelu(+bias)->bf16, 2=+bias+residual(f32), 3=f32 store
template <int EPI>
__global__ __launch_bounds__(256) void k_gemm(const unsigned short* __restrict__ A,
                                              const unsigned short* __restrict__ BT,
                                              const float* __restrict__ bias,
                                              float* __restrict__ resid,
                                              unsigned short* __restrict__ outb,
                                              float* __restrict__ outf,
                                              int N, int K) {
  __shared__ unsigned short As[128 * 72];
  __shared__ unsigned short Bs[128 * 72];
  int tid = threadIdx.x;
  int wid = tid >> 6, lane = tid & 63;
  int lr = lane & 15, lg = lane >> 4;
  int m0 = blockIdx.x * 128, n0 = blockIdx.y * 128;
  int wm = (wid >> 1) * 64, wn = (wid & 1) * 64;

  fx4 acc[4][4] = {};

  for (int kt = 0; kt < K; kt += 64) {
    __syncthreads();
#pragma unroll
    for (int i = 0; i < 4; ++i) {
      int chunk = i * 256 + tid;                 // 1024 chunks of 8 bf16
      int r = chunk >> 3, c = (chunk & 7) << 3;
      *(uix4*)&As[r * 72 + c] = *(const uix4*)&A[(size_t)(m0 + r) * K + kt + c];
      *(uix4*)&Bs[r * 72 + c] = *(const uix4*)&BT[(size_t)(n0 + r) * K + kt + c];
    }
    __syncthreads();
#pragma unroll
    for (int kk = 0; kk < 2; ++kk) {
      sx8 fa[4], fb[4];
#pragma unroll
      for (int mi = 0; mi < 4; ++mi)
        fa[mi] = *(const sx8*)&As[(wm + mi * 16 + lr) * 72 + kk * 32 + lg * 8];
#pragma unroll
      for (int ni = 0; ni < 4; ++ni)
        fb[ni] = *(const sx8*)&Bs[(wn + ni * 16 + lr) * 72 + kk * 32 + lg * 8];
#pragma unroll
      for (int mi = 0; mi < 4; ++mi)
#pragma unroll
        for (int ni = 0; ni < 4; ++ni)
          acc[mi][ni] = __builtin_amdgcn_mfma_f32_16x16x32_bf16(fa[mi], fb[ni], acc[mi][ni], 0, 0, 0);
    }
  }

  // epilogue: D row = (lane>>4)*4 + reg, col = lane&15 within each 16x16 tile
#pragma unroll
  for (int ni = 0; ni < 4; ++ni) {
    int col = n0 + wn + ni * 16 + lr;
    float bv = bias ? bias[col] : 0.0f;
#pragma unroll
    for (int mi = 0; mi < 4; ++mi) {
#pragma unroll
      for (int rr = 0; rr < 4; ++rr) {
        int row = m0 + wm + mi * 16 + lg * 4 + rr;
        float val = acc[mi][ni][rr] + bv;
        if constexpr (EPI == 0) {  // qkv scatter -> [which][b,h,t,d] bf16
          int which = col >> 10;
          int hc = col & 1023;
          int bb = row >> 10, tt = row & 1023;
          outb[(size_t)which * NTOK * DM +
               (((size_t)bb * NH + (hc >> 6)) * T_SEQ + tt) * DH + (hc & 63)] = f2bf(val);
        } else if constexpr (EPI == 1) {  // exact GELU -> bf16
          float gv = 0.5f * val * (1.0f + erff(val * 0.70710678f));
          outb[(size_t)row * N + col] = f2bf(gv);
        } else if constexpr (EPI == 2) {  // residual accumulate f32
          resid[(size_t)row * N + col] += val;
        } else {  // logits f32
          outf[(size_t)row * N + col] = val;
        }
      }
    }
  }
}

// ---------------- flash attention ----------------
// grid (T/64, B*H). Block: 4 waves, wave w owns q rows qt*64+w*16 .. +15.
// K tile [64][64] and V^T tile [64][64] staged in LDS (72-elem padded rows).
// S = Q K^T via mfma (A=Q frags from global, B=K rows from LDS), f32 online softmax,
// P -> per-wave LDS -> A frags, y += P V via mfma (B = V^T rows from LDS).
__global__ __launch_bounds__(256) void k_attn(const unsigned short* __restrict__ gq,
                                              const unsigned short* __restrict__ gk,
                                              const unsigned short* __restrict__ gv,
                                              unsigned short* __restrict__ y) {
  __shared__ unsigned short Ks[64 * 72];
  __shared__ unsigned short Vt[64 * 72];
  __shared__ unsigned short Pw[4][16 * 72];
  int qt = blockIdx.x, bh = blockIdx.y;
  int tid = threadIdx.x, wid = tid >> 6, lane = tid & 63;
  int lr = lane & 15, lg = lane >> 4;
  int q0 = qt * 64 + wid * 16;

  sx8 qf[2];
  {
    const unsigned short* qp = gq + ((size_t)bh * T_SEQ + q0 + lr) * DH + lg * 8;
    qf[0] = *(const sx8*)qp;
    qf[1] = *(const sx8*)(qp + 32);
  }

  fx4 yacc[4] = {};
  float mrow[4] = {-1e30f, -1e30f, -1e30f, -1e30f};
  float lrow[4] = {0.f, 0.f, 0.f, 0.f};

  for (int ktile = 0; ktile <= qt; ++ktile) {
    int kt0 = ktile * 64;
    __syncthreads();
#pragma unroll
    for (int i = 0; i < 2; ++i) {
      int chunk = i * 256 + tid;
      int r = chunk >> 3, c = (chunk & 7) << 3;
      *(uix4*)&Ks[r * 72 + c] = *(const uix4*)&gk[((size_t)bh * T_SEQ + kt0 + r) * DH + c];
    }
    {
      int tv = tid >> 2, d0 = (tid & 3) << 4;
      const unsigned short* vp = gv + ((size_t)bh * T_SEQ + kt0 + tv) * DH + d0;
      usx8 v0 = *(const usx8*)vp;
      usx8 v1 = *(const usx8*)(vp + 8);
#pragma unroll
      for (int j = 0; j < 8; ++j) {
        Vt[(d0 + j) * 72 + tv] = v0[j];
        Vt[(d0 + 8 + j) * 72 + tv] = v1[j];
      }
    }
    __syncthreads();

    // S = Q K^T
    fx4 s[4] = {};
#pragma unroll
    for (int kk = 0; kk < 2; ++kk) {
#pragma unroll
      for (int ni = 0; ni < 4; ++ni) {
        sx8 kb = *(const sx8*)&Ks[(ni * 16 + lr) * 72 + kk * 32 + lg * 8];
        s[ni] = __builtin_amdgcn_mfma_f32_16x16x32_bf16(qf[kk], kb, s[ni], 0, 0, 0);
      }
    }

    // mask + scale + online softmax (rows = lg*4+rr, cols = ni*16+lr)
    float p[4][4];
#pragma unroll
    for (int rr = 0; rr < 4; ++rr) {
      int rowg = q0 + lg * 4 + rr;
      float pm = -1e30f;
#pragma unroll
      for (int ni = 0; ni < 4; ++ni) {
        int colg = kt0 + ni * 16 + lr;
        float val = s[ni][rr] * 0.125f;
        if (colg > rowg) val = -1e30f;
        p[ni][rr] = val;
        pm = fmaxf(pm, val);
      }
#pragma unroll
      for (int off = 1; off < 16; off <<= 1) pm = fmaxf(pm, __shfl_xor(pm, off, 16));
      float mnew = fmaxf(mrow[rr], pm);
      float sc = __expf(mrow[rr] - mnew);
      mrow[rr] = mnew;
      float ps = 0.f;
#pragma unroll
      for (int ni = 0; ni < 4; ++ni) {
        float e = __expf(p[ni][rr] - mnew);
        p[ni][rr] = e;
        ps += e;
      }
#pragma unroll
      for (int off = 1; off < 16; off <<= 1) ps += __shfl_xor(ps, off, 16);
      lrow[rr] = lrow[rr] * sc + ps;
#pragma unroll
      for (int ni = 0; ni < 4; ++ni) yacc[ni][rr] *= sc;
    }

    // P -> LDS (per-wave buffer), then PV
#pragma unroll
    for (int rr = 0; rr < 4; ++rr)
#pragma unroll
      for (int ni = 0; ni < 4; ++ni)
        Pw[wid][(lg * 4 + rr) * 72 + ni * 16 + lr] = f2bf(p[ni][rr]);

#pragma unroll
    for (int kk = 0; kk < 2; ++kk) {
      sx8 pa = *(const sx8*)&Pw[wid][lr * 72 + kk * 32 + lg * 8];
#pragma unroll
      for (int dt = 0; dt < 4; ++dt) {
        sx8 vb = *(const sx8*)&Vt[(dt * 16 + lr) * 72 + kk * 32 + lg * 8];
        yacc[dt] = __builtin_amdgcn_mfma_f32_16x16x32_bf16(pa, vb, yacc[dt], 0, 0, 0);
      }
    }
  }

  // epilogue: y[token][h*64+d] bf16, divide by row sum
  int b = bh >> 4, hh = bh & 15;
#pragma unroll
  for (int dt = 0; dt < 4; ++dt)
#pragma unroll
    for (int rr = 0; rr < 4; ++rr) {
      int tok = b * T_SEQ + q0 + lg * 4 + rr;
      int col = hh * DH + dt * 16 + lr;
      y[(size_t)tok * DM + col] = f2bf(yacc[dt][rr] / lrow[rr]);
    }
}

// ---------------- launcher ----------------
extern "C" void kernel_launch(void* const* d_in, const int* in_sizes, int n_in,
                              void* d_out, int out_size, void* d_ws, size_t ws_size,
                              hipStream_t stream) {
  (void)in_sizes; (void)n_in; (void)out_size; (void)ws_size;
  const int*   idx     = (const int*)d_in[0];
  const float* tok_emb = (const float*)d_in[1];
  const float* pos_emb = (const float*)d_in[2];
  const float* ln1_s   = (const float*)d_in[3];
  const float* ln1_b   = (const float*)d_in[4];
  const float* qkv_w   = (const float*)d_in[5];
  const float* qkv_b   = (const float*)d_in[6];
  const float* out_w   = (const float*)d_in[7];
  const float* out_b   = (const float*)d_in[8];
  const float* ln2_s   = (const float*)d_in[9];
  const float* ln2_b   = (const float*)d_in[10];
  const float* mlp_w1  = (const float*)d_in[11];
  const float* mlp_b1  = (const float*)d_in[12];
  const float* mlp_w2  = (const float*)d_in[13];
  const float* mlp_b2  = (const float*)d_in[14];
  const float* lnf_s   = (const float*)d_in[15];
  const float* lnf_b   = (const float*)d_in[16];
  const float* head_w  = (const float*)d_in[17];

  // workspace layout (~110 MB total)
  char* p = (char*)d_ws;
  float* x          = (float*)p;          p += (size_t)NTOK * DM * 4;   // 8 MB
  unsigned short* h = (unsigned short*)p; p += (size_t)NTOK * DM * 2;   // 4 MB
  unsigned short* qkvb = (unsigned short*)p; p += (size_t)3 * NTOK * DM * 2; // 12 MB
  unsigned short* yb = (unsigned short*)p; p += (size_t)NTOK * DM * 2;  // 4 MB
  unsigned short* m1 = (unsigned short*)p; p += (size_t)NTOK * DFF * 2; // 16 MB
  unsigned short* wt = (unsigned short*)p; p += (size_t)VOCAB * DM * 2; // 64 MB

  dim3 blk(256);

  k_embed<<<NTOK, blk, 0, stream>>>(idx, tok_emb, pos_emb, x);

  for (int l = 0; l < NL; ++l) {
    k_ln<<<NTOK, blk, 0, stream>>>(x, ln1_s + l * DM, ln1_b + l * DM, h);
    k_wtrans<<<dim3(DM / 64, 3 * DM / 64), blk, 0, stream>>>(qkv_w + (size_t)l * DM * 3 * DM, wt, DM, 3 * DM);
    k_gemm<0><<<dim3(16, 3 * DM / 128), blk, 0, stream>>>(h, wt, qkv_b + l * 3 * DM,
                                                          nullptr, qkvb, nullptr, 3 * DM, DM);
    k_attn<<<dim3(T_SEQ / 64, 2 * NH), blk, 0, stream>>>(qkvb, qkvb + (size_t)NTOK * DM,
                                                         qkvb + (size_t)2 * NTOK * DM, yb);
    k_wtrans<<<dim3(DM / 64, DM / 64), blk, 0, stream>>>(out_w + (size_t)l * DM * DM, wt, DM, DM);
    k_gemm<2><<<dim3(16, DM / 128), blk, 0, stream>>>(yb, wt, out_b + l * DM,
                                                      x, nullptr, nullptr, DM, DM);
    k_ln<<<NTOK, blk, 0, stream>>>(x, ln2_s + l * DM, ln2_b + l * DM, h);
    k_wtrans<<<dim3(DM / 64, DFF / 64), blk, 0, stream>>>(mlp_w1 + (size_t)l * DM * DFF, wt, DM, DFF);
    k_gemm<1><<<dim3(16, DFF / 128), blk, 0, stream>>>(h, wt, mlp_b1 + l * DFF,
                                                       nullptr, m1, nullptr, DFF, DM);
    k_wtrans<<<dim3(DFF / 64, DM / 64), blk, 0, stream>>>(mlp_w2 + (size_t)l * DFF * DM, wt, DFF, DM);
    k_gemm<2><<<dim3(16, DM / 128), blk, 0, stream>>>(m1, wt, mlp_b2 + l * DM,
                                                      x, nullptr, nullptr, DM, DFF);
  }

  k_ln<<<NTOK, blk, 0, stream>>>(x, lnf_s, lnf_b, h);
  k_wtrans<<<dim3(DM / 64, VOCAB / 64), blk, 0, stream>>>(head_w, wt, DM, VOCAB);
  k_gemm<3><<<dim3(16, VOCAB / 128), blk, 0, stream>>>(h, wt, nullptr,
                                                       nullptr, nullptr, (float*)d_out, VOCAB, DM);
}

// Round 2
// 1471.018 us; speedup vs baseline: 1.1887x; 1.1887x over previous
//
#include <hip/hip_runtime.h>

// GPT2-like forward, MI355X. Round 2:
// - GEMM: m97 structure (global_load_lds width=16, linear LDS + XOR slot swizzle)
// - XCD-chunked bijective block swizzle, 1-D grid
// - split-K=4 + atomicAdd epilogue for N=1024 GEMMs (occupancy)
// - attention: swapped QK^T (S^T), lane-local softmax rows

#define T_SEQ 1024
#define NTOK  2048   // B*T
#define DM    1024
#define DFF   4096
#define NH    16
#define DH    64
#define NL    6
#define VOCAB 32000

typedef short sx8 __attribute__((ext_vector_type(8)));          // 8 bf16 (4 VGPR) MFMA frag
typedef float fx4 __attribute__((ext_vector_type(4)));          // MFMA acc
typedef unsigned short usx4 __attribute__((ext_vector_type(4)));
typedef unsigned short usx8 __attribute__((ext_vector_type(8)));
typedef unsigned int   uix4 __attribute__((ext_vector_type(4))); // 16B copy

__device__ __forceinline__ unsigned short f2bf(float f) {
  union { float f; unsigned u; } c; c.f = f;
  unsigned r = c.u + 0x7FFFu + ((c.u >> 16) & 1u);   // round-nearest-even
  return (unsigned short)(r >> 16);
}

__device__ __forceinline__ void gload_lds16(const unsigned short* g, unsigned short* l) {
  __builtin_amdgcn_global_load_lds(
      (const __attribute__((address_space(1))) unsigned int*)g,
      (__attribute__((address_space(3))) unsigned int*)l, 16, 0, 0);
}

// bijective XCD-chunked swizzle (m204): round-robin hw dispatch -> contiguous chunks/XCD
__device__ __forceinline__ int xcd_swizzle(int orig, int nwg) {
  int q = nwg >> 3, r = nwg & 7;
  int xcd = orig & 7, idx = orig >> 3;
  int base = (xcd < r) ? xcd * (q + 1) : r * (q + 1) + (xcd - r) * q;
  return base + idx;
}

// ---------------- embedding: x = tok_emb[idx] + pos_emb ----------------
__global__ __launch_bounds__(256) void k_embed(const int* __restrict__ idx,
                                               const float* __restrict__ tok,
                                               const float* __restrict__ pos,
                                               float* __restrict__ x) {
  int token = blockIdx.x;
  int t = token & (T_SEQ - 1);
  int id = idx[token];
  int c = threadIdx.x * 4;
  float4 tv = *(const float4*)&tok[(size_t)id * DM + c];
  float4 pv = *(const float4*)&pos[(size_t)t * DM + c];
  float4 r;
  r.x = tv.x + pv.x; r.y = tv.y + pv.y; r.z = tv.z + pv.z; r.w = tv.w + pv.w;
  *(float4*)&x[(size_t)token * DM + c] = r;
}

// ---------------- layernorm: h(bf16) = LN(x)*g + b ----------------
__global__ __launch_bounds__(256) void k_ln(const float* __restrict__ x,
                                            const float* __restrict__ g,
                                            const float* __restrict__ b,
                                            unsigned short* __restrict__ h) {
  int row = blockIdx.x;
  int tid = threadIdx.x;
  float4 v = *(const float4*)&x[(size_t)row * DM + tid * 4];
  float s = v.x + v.y + v.z + v.w;
  float q = v.x * v.x + v.y * v.y + v.z * v.z + v.w * v.w;
  for (int off = 32; off > 0; off >>= 1) {
    s += __shfl_down(s, off);
    q += __shfl_down(q, off);
  }
  __shared__ float red[8];
  int wid = tid >> 6, lane = tid & 63;
  if (lane == 0) { red[wid] = s; red[4 + wid] = q; }
  __syncthreads();
  s = red[0] + red[1] + red[2] + red[3];
  q = red[4] + red[5] + red[6] + red[7];
  float mu = s * (1.0f / DM);
  float var = q * (1.0f / DM) - mu * mu;
  float rstd = rsqrtf(var + 1e-5f);
  float4 gg = *(const float4*)&g[tid * 4];
  float4 bb = *(const float4*)&b[tid * 4];
  usx4 o;
  o[0] = f2bf((v.x - mu) * rstd * gg.x + bb.x);
  o[1] = f2bf((v.y - mu) * rstd * gg.y + bb.y);
  o[2] = f2bf((v.z - mu) * rstd * gg.z + bb.z);
  o[3] = f2bf((v.w - mu) * rstd * gg.w + bb.w);
  *(usx4*)&h[(size_t)row * DM + tid * 4] = o;
}

// ---------------- weight convert+transpose: WT[n][k] = bf16(W[k][n]) ----------------
__global__ __launch_bounds__(256) void k_wtrans(const float* __restrict__ W,
                                                unsigned short* __restrict__ WT,
                                                int K, int N) {
  __shared__ float t[64][68];
  int k0 = blockIdx.x * 64, n0 = blockIdx.y * 64;
  int tid = threadIdx.x;
#pragma unroll
  for (int i = 0; i < 4; ++i) {
    int chunk = i * 256 + tid;
    int r = chunk >> 4, c = (chunk & 15) << 2;
    float4 v = *(const float4*)&W[(size_t)(k0 + r) * N + n0 + c];
    t[r][c] = v.x; t[r][c + 1] = v.y; t[r][c + 2] = v.z; t[r][c + 3] = v.w;
  }
  __syncthreads();
#pragma unroll
  for (int i = 0; i < 4; ++i) {
    int chunk = i * 256 + tid;
    int n = chunk >> 4, c = (chunk & 15) << 2;
    usx4 o;
    o[0] = f2bf(t[c][n]);
    o[1] = f2bf(t[c + 1][n]);
    o[2] = f2bf(t[c + 2][n]);
    o[3] = f2bf(t[c + 3][n]);
    *(usx4*)&WT[(size_t)(n0 + n) * K + k0 + c] = o;
  }
}

// ---------------- GEMM v2: C[M=2048,N] = A[M,K](bf16) * BT[N,K]^T(bf16) ----------------
// m97 structure: 128x128 tile, BK=64, 4 waves (2x2), global_load_lds width=16,
// linear LDS [128][64] with XOR slot swizzle (pre-swizzled global source + swizzled read).
// EPI: 0=qkv scatter(+bias), 1=gelu(+bias)->bf16, 2=+bias, atomicAdd residual(f32), 3=f32 store
template <int EPI>
__global__ __launch_bounds__(256) void k_gemm(const unsigned short* __restrict__ A,
                                              const unsigned short* __restrict__ BT,
                                              const float* __restrict__ bias,
                                              float* __restrict__ resid,
                                              unsigned short* __restrict__ outb,
                                              float* __restrict__ outf,
                                              int N, int K, int NT, int KS) {
  __shared__ unsigned short As[128 * 64];
  __shared__ unsigned short Bs[128 * 64];
  int tid = threadIdx.x;
  int wid = tid >> 6, lane = tid & 63;
  int lr = lane & 15, lg = lane >> 4;

  int id = xcd_swizzle(blockIdx.x, gridDim.x);
  int mt = id & 15;                 // MT = 16 (M=2048/128), fastest -> shares B panel
  int rest = id >> 4;
  int nt = rest % NT;
  int ks = rest / NT;
  int m0 = mt * 128, n0 = nt * 128;
  int Kslice = K / KS;
  int kbeg = ks * Kslice, kend = kbeg + Kslice;

  int wm = (wid >> 1) * 64, wn = (wid & 1) * 64;

  fx4 acc[4][4] = {};

  for (int kt = kbeg; kt < kend; kt += 64) {
    __syncthreads();
#pragma unroll
    for (int i = 0; i < 4; ++i) {
      int chunk = i * 256 + tid;                 // 1024 chunks of 16 B
      int r = chunk >> 3;
      int slot = chunk & 7;
      int c = ((slot ^ (r & 7)) << 3);           // inverse-swizzled source column
      gload_lds16(&A[(size_t)(m0 + r) * K + kt + c], &As[chunk << 3]);
      gload_lds16(&BT[(size_t)(n0 + r) * K + kt + c], &Bs[chunk << 3]);
    }
    __syncthreads();                             // compiler drains vmcnt(0) here
#pragma unroll
    for (int kk = 0; kk < 2; ++kk) {
      int slotz = (kk * 4 + lg) ^ (lr & 7);      // swizzled read slot
      sx8 fa[4], fb[4];
#pragma unroll
      for (int mi = 0; mi < 4; ++mi)
        fa[mi] = *(const sx8*)&As[(wm + mi * 16 + lr) * 64 + slotz * 8];
#pragma unroll
      for (int ni = 0; ni < 4; ++ni)
        fb[ni] = *(const sx8*)&Bs[(wn + ni * 16 + lr) * 64 + slotz * 8];
#pragma unroll
      for (int mi = 0; mi < 4; ++mi)
#pragma unroll
        for (int ni = 0; ni < 4; ++ni)
          acc[mi][ni] = __builtin_amdgcn_mfma_f32_16x16x32_bf16(fa[mi], fb[ni], acc[mi][ni], 0, 0, 0);
    }
  }

  // epilogue: D row = (lane>>4)*4 + reg, col = lane&15 within each 16x16 tile
#pragma unroll
  for (int ni = 0; ni < 4; ++ni) {
    int col = n0 + wn + ni * 16 + lr;
    float bv = (bias && ks == 0) ? bias[col] : 0.0f;
#pragma unroll
    for (int mi = 0; mi < 4; ++mi) {
#pragma unroll
      for (int rr = 0; rr < 4; ++rr) {
        int row = m0 + wm + mi * 16 + lg * 4 + rr;
        float val = acc[mi][ni][rr] + bv;
        if constexpr (EPI == 0) {  // qkv scatter -> [which][b,h,t,d] bf16
          int which = col >> 10;
          int hc = col & 1023;
          int bb = row >> 10, tt = row & 1023;
          outb[(size_t)which * NTOK * DM +
               (((size_t)bb * NH + (hc >> 6)) * T_SEQ + tt) * DH + (hc & 63)] = f2bf(val);
        } else if constexpr (EPI == 1) {  // exact GELU -> bf16
          float gv = 0.5f * val * (1.0f + erff(val * 0.70710678f));
          outb[(size_t)row * N + col] = f2bf(gv);
        } else if constexpr (EPI == 2) {  // residual accumulate f32 (split-K safe)
          atomicAdd(&resid[(size_t)row * N + col], val);
        } else {  // logits f32
          outf[(size_t)row * N + col] = val;
        }
      }
    }
  }
}

// ---------------- flash attention (swapped QK^T) ----------------
// grid (T/64, B*H). Block: 4 waves, wave w owns q rows qt*64+w*16 .. +15.
// S^T = mfma(K_frag, Q_frag): lane (lr,lg) holds q-row lr, keys mi*16+lg*4+reg.
// Softmax: lane-local 16 values + 2 shfl_xor (16,32). P^T packed -> LDS -> PV.
__global__ __launch_bounds__(256) void k_attn(const unsigned short* __restrict__ gq,
                                              const unsigned short* __restrict__ gk,
                                              const unsigned short* __restrict__ gv,
                                              unsigned short* __restrict__ y) {
  __shared__ unsigned short Ks[64 * 72];
  __shared__ unsigned short Vt[64 * 72];
  __shared__ unsigned short Pw[4][16 * 72];
  int qt = blockIdx.x, bh = blockIdx.y;
  int tid = threadIdx.x, wid = tid >> 6, lane = tid & 63;
  int lr = lane & 15, lg = lane >> 4;
  int q0 = qt * 64 + wid * 16;

  sx8 qf[2];
  {
    const unsigned short* qp = gq + ((size_t)bh * T_SEQ + q0 + lr) * DH + lg * 8;
    qf[0] = *(const sx8*)qp;
    qf[1] = *(const sx8*)(qp + 32);
  }

  fx4 yacc[4] = {};
  float mrun = -1e30f;   // running max for q-row lr (replicated across lg)
  float lrun = 0.f;      // running sum for q-row lr

  for (int ktile = 0; ktile <= qt; ++ktile) {
    int kt0 = ktile * 64;
    __syncthreads();
#pragma unroll
    for (int i = 0; i < 2; ++i) {
      int chunk = i * 256 + tid;
      int r = chunk >> 3, c = (chunk & 7) << 3;
      *(uix4*)&Ks[r * 72 + c] = *(const uix4*)&gk[((size_t)bh * T_SEQ + kt0 + r) * DH + c];
    }
    {
      int tv = tid >> 2, d0 = (tid & 3) << 4;
      const unsigned short* vp = gv + ((size_t)bh * T_SEQ + kt0 + tv) * DH + d0;
      usx8 v0 = *(const usx8*)vp;
      usx8 v1 = *(const usx8*)(vp + 8);
#pragma unroll
      for (int j = 0; j < 8; ++j) {
        Vt[(d0 + j) * 72 + tv] = v0[j];
        Vt[(d0 + 8 + j) * 72 + tv] = v1[j];
      }
    }
    __syncthreads();

    // S^T = K Q^T : st[mi] rows = keys, cols = q
    fx4 st[4] = {};
#pragma unroll
    for (int kk = 0; kk < 2; ++kk) {
#pragma unroll
      for (int mi = 0; mi < 4; ++mi) {
        sx8 kb = *(const sx8*)&Ks[(mi * 16 + lr) * 72 + kk * 32 + lg * 8];
        st[mi] = __builtin_amdgcn_mfma_f32_16x16x32_bf16(kb, qf[kk], st[mi], 0, 0, 0);
      }
    }

    // lane-local softmax: this lane's q-row = lr, keys = kt0 + mi*16 + lg*4 + reg
    int qg = q0 + lr;
    float pv[4][4];
    float pmax = -1e30f;
#pragma unroll
    for (int mi = 0; mi < 4; ++mi)
#pragma unroll
      for (int rg = 0; rg < 4; ++rg) {
        int ksg = kt0 + mi * 16 + lg * 4 + rg;
        float val = st[mi][rg] * 0.125f;
        if (ksg > qg) val = -1e30f;
        pv[mi][rg] = val;
        pmax = fmaxf(pmax, val);
      }
    pmax = fmaxf(pmax, __shfl_xor(pmax, 16));
    pmax = fmaxf(pmax, __shfl_xor(pmax, 32));
    float mnew = fmaxf(mrun, pmax);
    float sc = __expf(mrun - mnew);
    mrun = mnew;
    float ps = 0.f;
#pragma unroll
    for (int mi = 0; mi < 4; ++mi)
#pragma unroll
      for (int rg = 0; rg < 4; ++rg) {
        float e = __expf(pv[mi][rg] - mnew);
        pv[mi][rg] = e;
        ps += e;
      }
    ps += __shfl_xor(ps, 16);
    ps += __shfl_xor(ps, 32);
    lrun = lrun * sc + ps;

    // P^T -> Pw[wid] rows q=lr, cols k (packed pairs)
#pragma unroll
    for (int mi = 0; mi < 4; ++mi)
#pragma unroll
      for (int rp = 0; rp < 2; ++rp) {
        unsigned pk = (unsigned)f2bf(pv[mi][rp * 2]) |
                      ((unsigned)f2bf(pv[mi][rp * 2 + 1]) << 16);
        *(unsigned*)&Pw[wid][lr * 72 + mi * 16 + lg * 4 + rp * 2] = pk;
      }

    // rescale yacc (rows q = lg*4+reg): fetch sc from lane q
    float scq[4];
#pragma unroll
    for (int rg = 0; rg < 4; ++rg) scq[rg] = __shfl(sc, lg * 4 + rg, 64);
#pragma unroll
    for (int dt = 0; dt < 4; ++dt)
#pragma unroll
      for (int rg = 0; rg < 4; ++rg) yacc[dt][rg] *= scq[rg];

    // PV
#pragma unroll
    for (int kk = 0; kk < 2; ++kk) {
      sx8 pa = *(const sx8*)&Pw[wid][lr * 72 + kk * 32 + lg * 8];
#pragma unroll
      for (int dt = 0; dt < 4; ++dt) {
        sx8 vb = *(const sx8*)&Vt[(dt * 16 + lr) * 72 + kk * 32 + lg * 8];
        yacc[dt] = __builtin_amdgcn_mfma_f32_16x16x32_bf16(pa, vb, yacc[dt], 0, 0, 0);
      }
    }
  }

  // epilogue: divide by row sum (rows q = lg*4+reg)
  float lq[4];
#pragma unroll
  for (int rg = 0; rg < 4; ++rg) lq[rg] = __shfl(lrun, lg * 4 + rg, 64);
  int b = bh >> 4, hh = bh & 15;
#pragma unroll
  for (int dt = 0; dt < 4; ++dt)
#pragma unroll
    for (int rg = 0; rg < 4; ++rg) {
      int tok = b * T_SEQ + q0 + lg * 4 + rg;
      int col = hh * DH + dt * 16 + lr;
      y[(size_t)tok * DM + col] = f2bf(yacc[dt][rg] / lq[rg]);
    }
}

// ---------------- launcher ----------------
extern "C" void kernel_launch(void* const* d_in, const int* in_sizes, int n_in,
                              void* d_out, int out_size, void* d_ws, size_t ws_size,
                              hipStream_t stream) {
  (void)in_sizes; (void)n_in; (void)out_size; (void)ws_size;
  const int*   idx     = (const int*)d_in[0];
  const float* tok_emb = (const float*)d_in[1];
  const float* pos_emb = (const float*)d_in[2];
  const float* ln1_s   = (const float*)d_in[3];
  const float* ln1_b   = (const float*)d_in[4];
  const float* qkv_w   = (const float*)d_in[5];
  const float* qkv_b   = (const float*)d_in[6];
  const float* out_w   = (const float*)d_in[7];
  const float* out_b   = (const float*)d_in[8];
  const float* ln2_s   = (const float*)d_in[9];
  const float* ln2_b   = (const float*)d_in[10];
  const float* mlp_w1  = (const float*)d_in[11];
  const float* mlp_b1  = (const float*)d_in[12];
  const float* mlp_w2  = (const float*)d_in[13];
  const float* mlp_b2  = (const float*)d_in[14];
  const float* lnf_s   = (const float*)d_in[15];
  const float* lnf_b   = (const float*)d_in[16];
  const float* head_w  = (const float*)d_in[17];

  // workspace layout (~110 MB total)
  char* p = (char*)d_ws;
  float* x          = (float*)p;          p += (size_t)NTOK * DM * 4;   // 8 MB
  unsigned short* h = (unsigned short*)p; p += (size_t)NTOK * DM * 2;   // 4 MB
  unsigned short* qkvb = (unsigned short*)p; p += (size_t)3 * NTOK * DM * 2; // 12 MB
  unsigned short* yb = (unsigned short*)p; p += (size_t)NTOK * DM * 2;  // 4 MB
  unsigned short* m1 = (unsigned short*)p; p += (size_t)NTOK * DFF * 2; // 16 MB
  unsigned short* wt = (unsigned short*)p; p += (size_t)VOCAB * DM * 2; // 64 MB

  dim3 blk(256);

  k_embed<<<NTOK, blk, 0, stream>>>(idx, tok_emb, pos_emb, x);

  for (int l = 0; l < NL; ++l) {
    k_ln<<<NTOK, blk, 0, stream>>>(x, ln1_s + l * DM, ln1_b + l * DM, h);
    k_wtrans<<<dim3(DM / 64, 3 * DM / 64), blk, 0, stream>>>(qkv_w + (size_t)l * DM * 3 * DM, wt, DM, 3 * DM);
    // qkv: N=3072, NT=24, KS=1 -> 384 blocks
    k_gemm<0><<<16 * 24, blk, 0, stream>>>(h, wt, qkv_b + l * 3 * DM,
                                           nullptr, qkvb, nullptr, 3 * DM, DM, 24, 1);
    k_attn<<<dim3(T_SEQ / 64, 2 * NH), blk, 0, stream>>>(qkvb, qkvb + (size_t)NTOK * DM,
                                                         qkvb + (size_t)2 * NTOK * DM, yb);
    k_wtrans<<<dim3(DM / 64, DM / 64), blk, 0, stream>>>(out_w + (size_t)l * DM * DM, wt, DM, DM);
    // attn-out: N=1024, NT=8, KS=4 -> 512 blocks
    k_gemm<2><<<16 * 8 * 4, blk, 0, stream>>>(yb, wt, out_b + l * DM,
                                              x, nullptr, nullptr, DM, DM, 8, 4);
    k_ln<<<NTOK, blk, 0, stream>>>(x, ln2_s + l * DM, ln2_b + l * DM, h);
    k_wtrans<<<dim3(DM / 64, DFF / 64), blk, 0, stream>>>(mlp_w1 + (size_t)l * DM * DFF, wt, DM, DFF);
    // mlp1: N=4096, NT=32, KS=1 -> 512 blocks
    k_gemm<1><<<16 * 32, blk, 0, stream>>>(h, wt, mlp_b1 + l * DFF,
                                           nullptr, m1, nullptr, DFF, DM, 32, 1);
    k_wtrans<<<dim3(DFF / 64, DM / 64), blk, 0, stream>>>(mlp_w2 + (size_t)l * DFF * DM, wt, DFF, DM);
    // mlp2: N=1024, K=4096, NT=8, KS=4 -> 512 blocks
    k_gemm<2><<<16 * 8 * 4, blk, 0, stream>>>(m1, wt, mlp_b2 + l * DM,
                                              x, nullptr, nullptr, DM, DFF, 8, 4);
  }

  k_ln<<<NTOK, blk, 0, stream>>>(x, lnf_s, lnf_b, h);
  k_wtrans<<<dim3(DM / 64, VOCAB / 64), blk, 0, stream>>>(head_w, wt, DM, VOCAB);
  // head: N=32000, NT=250, KS=1 -> 4000 blocks
  k_gemm<3><<<16 * 250, blk, 0, stream>>>(h, wt, nullptr,
                                          nullptr, nullptr, (float*)d_out, VOCAB, DM, 250, 1);
}

// Round 3
// 1324.421 us; speedup vs baseline: 1.3203x; 1.1107x over previous
//
#include <hip/hip_runtime.h>

// GPT2-like forward, MI355X. Round 3:
// - attention: KVBLK=128, V pre-transposed by qkv epilogue, gload_lds staging
//   with XOR swizzle, PV operand-swapped (lane-local softmax state, 0 shuffles)
// - all GEMMs: C^T accumulation (mfma(fb,fa)) -> packed epilogue stores
// - split-K partials + fused reduce+residual+LN kernel (no atomics)

#define T_SEQ 1024
#define NTOK  2048   // B*T
#define DM    1024
#define DFF   4096
#define NH    16
#define DH    64
#define NL    6
#define VOCAB 32000

typedef short sx8 __attribute__((ext_vector_type(8)));          // 8 bf16 (4 VGPR) MFMA frag
typedef float fx4 __attribute__((ext_vector_type(4)));          // MFMA acc
typedef unsigned short usx4 __attribute__((ext_vector_type(4)));
typedef unsigned int   uix4 __attribute__((ext_vector_type(4))); // 16B copy

__device__ __forceinline__ unsigned short f2bf(float f) {
  union { float f; unsigned u; } c; c.f = f;
  unsigned r = c.u + 0x7FFFu + ((c.u >> 16) & 1u);   // round-nearest-even
  return (unsigned short)(r >> 16);
}

__device__ __forceinline__ void gload_lds16(const unsigned short* g, unsigned short* l) {
  __builtin_amdgcn_global_load_lds(
      (const __attribute__((address_space(1))) unsigned int*)g,
      (__attribute__((address_space(3))) unsigned int*)l, 16, 0, 0);
}

// bijective XCD-chunked swizzle (m204)
__device__ __forceinline__ int xcd_swizzle(int orig, int nwg) {
  int q = nwg >> 3, r = nwg & 7;
  int xcd = orig & 7, idx = orig >> 3;
  int base = (xcd < r) ? xcd * (q + 1) : r * (q + 1) + (xcd - r) * q;
  return base + idx;
}

// ---------------- embedding ----------------
__global__ __launch_bounds__(256) void k_embed(const int* __restrict__ idx,
                                               const float* __restrict__ tok,
                                               const float* __restrict__ pos,
                                               float* __restrict__ x) {
  int token = blockIdx.x;
  int t = token & (T_SEQ - 1);
  int id = idx[token];
  int c = threadIdx.x * 4;
  float4 tv = *(const float4*)&tok[(size_t)id * DM + c];
  float4 pv = *(const float4*)&pos[(size_t)t * DM + c];
  float4 r;
  r.x = tv.x + pv.x; r.y = tv.y + pv.y; r.z = tv.z + pv.z; r.w = tv.w + pv.w;
  *(float4*)&x[(size_t)token * DM + c] = r;
}

// ---------------- layernorm (standalone, layer-0 ln1 only) ----------------
__global__ __launch_bounds__(256) void k_ln(const float* __restrict__ x,
                                            const float* __restrict__ g,
                                            const float* __restrict__ b,
                                            unsigned short* __restrict__ h) {
  int row = blockIdx.x;
  int tid = threadIdx.x;
  float4 v = *(const float4*)&x[(size_t)row * DM + tid * 4];
  float s = v.x + v.y + v.z + v.w;
  float q = v.x * v.x + v.y * v.y + v.z * v.z + v.w * v.w;
  for (int off = 32; off > 0; off >>= 1) {
    s += __shfl_down(s, off);
    q += __shfl_down(q, off);
  }
  __shared__ float red[8];
  int wid = tid >> 6, lane = tid & 63;
  if (lane == 0) { red[wid] = s; red[4 + wid] = q; }
  __syncthreads();
  s = red[0] + red[1] + red[2] + red[3];
  q = red[4] + red[5] + red[6] + red[7];
  float mu = s * (1.0f / DM);
  float var = q * (1.0f / DM) - mu * mu;
  float rstd = rsqrtf(var + 1e-5f);
  float4 gg = *(const float4*)&g[tid * 4];
  float4 bb = *(const float4*)&b[tid * 4];
  usx4 o;
  o[0] = f2bf((v.x - mu) * rstd * gg.x + bb.x);
  o[1] = f2bf((v.y - mu) * rstd * gg.y + bb.y);
  o[2] = f2bf((v.z - mu) * rstd * gg.z + bb.z);
  o[3] = f2bf((v.w - mu) * rstd * gg.w + bb.w);
  *(usx4*)&h[(size_t)row * DM + tid * 4] = o;
}

// ------------- fused split-K reduce + residual + layernorm -------------
// x[row] += sum_s part[s][row]; h[row] = LN(x[row])*g + b
__global__ __launch_bounds__(256) void k_reduce_ln(const float* __restrict__ part,
                                                   float* __restrict__ x,
                                                   const float* __restrict__ g,
                                                   const float* __restrict__ b,
                                                   unsigned short* __restrict__ h) {
  int row = blockIdx.x;
  int tid = threadIdx.x;
  int c = tid * 4;
  float4 v = *(const float4*)&x[(size_t)row * DM + c];
#pragma unroll
  for (int s4 = 0; s4 < 4; ++s4) {
    float4 p = *(const float4*)&part[((size_t)s4 * NTOK + row) * DM + c];
    v.x += p.x; v.y += p.y; v.z += p.z; v.w += p.w;
  }
  *(float4*)&x[(size_t)row * DM + c] = v;
  float s = v.x + v.y + v.z + v.w;
  float q = v.x * v.x + v.y * v.y + v.z * v.z + v.w * v.w;
  for (int off = 32; off > 0; off >>= 1) {
    s += __shfl_down(s, off);
    q += __shfl_down(q, off);
  }
  __shared__ float red[8];
  int wid = tid >> 6, lane = tid & 63;
  if (lane == 0) { red[wid] = s; red[4 + wid] = q; }
  __syncthreads();
  s = red[0] + red[1] + red[2] + red[3];
  q = red[4] + red[5] + red[6] + red[7];
  float mu = s * (1.0f / DM);
  float var = q * (1.0f / DM) - mu * mu;
  float rstd = rsqrtf(var + 1e-5f);
  float4 gg = *(const float4*)&g[c];
  float4 bb = *(const float4*)&b[c];
  usx4 o;
  o[0] = f2bf((v.x - mu) * rstd * gg.x + bb.x);
  o[1] = f2bf((v.y - mu) * rstd * gg.y + bb.y);
  o[2] = f2bf((v.z - mu) * rstd * gg.z + bb.z);
  o[3] = f2bf((v.w - mu) * rstd * gg.w + bb.w);
  *(usx4*)&h[(size_t)row * DM + c] = o;
}

// ---------------- weight convert+transpose: WT[n][k] = bf16(W[k][n]) ----------------
__global__ __launch_bounds__(256) void k_wtrans(const float* __restrict__ W,
                                                unsigned short* __restrict__ WT,
                                                int K, int N) {
  __shared__ float t[64][68];
  int k0 = blockIdx.x * 64, n0 = blockIdx.y * 64;
  int tid = threadIdx.x;
#pragma unroll
  for (int i = 0; i < 4; ++i) {
    int chunk = i * 256 + tid;
    int r = chunk >> 4, c = (chunk & 15) << 2;
    float4 v = *(const float4*)&W[(size_t)(k0 + r) * N + n0 + c];
    t[r][c] = v.x; t[r][c + 1] = v.y; t[r][c + 2] = v.z; t[r][c + 3] = v.w;
  }
  __syncthreads();
#pragma unroll
  for (int i = 0; i < 4; ++i) {
    int chunk = i * 256 + tid;
    int n = chunk >> 4, c = (chunk & 15) << 2;
    usx4 o;
    o[0] = f2bf(t[c][n]);
    o[1] = f2bf(t[c + 1][n]);
    o[2] = f2bf(t[c + 2][n]);
    o[3] = f2bf(t[c + 3][n]);
    *(usx4*)&WT[(size_t)(n0 + n) * K + k0 + c] = o;
  }
}

// ---------------- GEMM: C[M=2048,N] = A[M,K](bf16) * BT[N,K]^T(bf16) ----------------
// m97 structure, C^T accumulation: lane holds (row=lr fixed, 4 consecutive cols).
// EPI: 0=qkv scatter(+bias, V transposed), 1=gelu(+bias)->bf16,
//      2=+bias -> f32 partial slice, 3=f32 store
template <int EPI>
__global__ __launch_bounds__(256) void k_gemm(const unsigned short* __restrict__ A,
                                              const unsigned short* __restrict__ BT,
                                              const float* __restrict__ bias,
                                              float* __restrict__ part,
                                              unsigned short* __restrict__ outb,
                                              float* __restrict__ outf,
                                              int N, int K, int NT, int KS) {
  __shared__ unsigned short As[128 * 64];
  __shared__ unsigned short Bs[128 * 64];
  int tid = threadIdx.x;
  int wid = tid >> 6, lane = tid & 63;
  int lr = lane & 15, lg = lane >> 4;

  int id = xcd_swizzle(blockIdx.x, gridDim.x);
  int mt = id & 15;
  int rest = id >> 4;
  int nt = rest % NT;
  int ks = rest / NT;
  int m0 = mt * 128, n0 = nt * 128;
  int Kslice = K / KS;
  int kbeg = ks * Kslice, kend = kbeg + Kslice;

  int wm = (wid >> 1) * 64, wn = (wid & 1) * 64;

  fx4 acc[4][4] = {};

  for (int kt = kbeg; kt < kend; kt += 64) {
    __syncthreads();
#pragma unroll
    for (int i = 0; i < 4; ++i) {
      int chunk = i * 256 + tid;                 // 1024 chunks of 16 B
      int r = chunk >> 3;
      int slot = chunk & 7;
      int c = ((slot ^ (r & 7)) << 3);           // inverse-swizzled source column
      gload_lds16(&A[(size_t)(m0 + r) * K + kt + c], &As[chunk << 3]);
      gload_lds16(&BT[(size_t)(n0 + r) * K + kt + c], &Bs[chunk << 3]);
    }
    __syncthreads();
#pragma unroll
    for (int kk = 0; kk < 2; ++kk) {
      int slotz = (kk * 4 + lg) ^ (lr & 7);      // swizzled read slot
      sx8 fa[4], fb[4];
#pragma unroll
      for (int mi = 0; mi < 4; ++mi)
        fa[mi] = *(const sx8*)&As[(wm + mi * 16 + lr) * 64 + slotz * 8];
#pragma unroll
      for (int ni = 0; ni < 4; ++ni)
        fb[ni] = *(const sx8*)&Bs[(wn + ni * 16 + lr) * 64 + slotz * 8];
#pragma unroll
      for (int mi = 0; mi < 4; ++mi)
#pragma unroll
        for (int ni = 0; ni < 4; ++ni)
          acc[mi][ni] = __builtin_amdgcn_mfma_f32_16x16x32_bf16(fb[ni], fa[mi], acc[mi][ni], 0, 0, 0);
    }
  }

  // C^T epilogue: lane (lr,lg): row = tile_m + lr, cols = tile_n + lg*4 + reg
#pragma unroll
  for (int ni = 0; ni < 4; ++ni) {
    int col0 = n0 + wn + ni * 16 + lg * 4;
    float4 bv = {0.f, 0.f, 0.f, 0.f};
    if (bias && ks == 0) bv = *(const float4*)&bias[col0];
#pragma unroll
    for (int mi = 0; mi < 4; ++mi) {
      int row = m0 + wm + mi * 16 + lr;
      float v0 = acc[mi][ni][0] + bv.x;
      float v1 = acc[mi][ni][1] + bv.y;
      float v2 = acc[mi][ni][2] + bv.z;
      float v3 = acc[mi][ni][3] + bv.w;
      if constexpr (EPI == 0) {  // qkv scatter: q,k -> [b,h,t,d]; v -> [b,h,d,t]
        int bb = row >> 10, tt = row & 1023;
        if (col0 < 2048) {       // q or k
          int which = col0 >> 10;          // 0=q, 1=k
          int hc = col0 & 1023;
          usx4 o = {f2bf(v0), f2bf(v1), f2bf(v2), f2bf(v3)};
          *(usx4*)&outb[(size_t)which * NTOK * DM +
                        (((size_t)bb * NH + (hc >> 6)) * T_SEQ + tt) * DH + (hc & 63)] = o;
        } else {                 // v -> transposed [bh][d][t]
          int dc = col0 - 2048;
          unsigned short* vt = outb + (size_t)2 * NTOK * DM;
          size_t base = (((size_t)bb * NH + (dc >> 6)) * DH + (dc & 63)) * T_SEQ + tt;
          vt[base] = f2bf(v0);
          vt[base + T_SEQ] = f2bf(v1);
          vt[base + 2 * T_SEQ] = f2bf(v2);
          vt[base + 3 * T_SEQ] = f2bf(v3);
        }
      } else if constexpr (EPI == 1) {  // exact GELU -> bf16
        usx4 o;
        o[0] = f2bf(0.5f * v0 * (1.0f + erff(v0 * 0.70710678f)));
        o[1] = f2bf(0.5f * v1 * (1.0f + erff(v1 * 0.70710678f)));
        o[2] = f2bf(0.5f * v2 * (1.0f + erff(v2 * 0.70710678f)));
        o[3] = f2bf(0.5f * v3 * (1.0f + erff(v3 * 0.70710678f)));
        *(usx4*)&outb[(size_t)row * N + col0] = o;
      } else if constexpr (EPI == 2) {  // f32 partial slice (split-K)
        float4 o = {v0, v1, v2, v3};
        *(float4*)&part[((size_t)ks * NTOK + row) * DM + col0] = o;
      } else {  // logits f32
        float4 o = {v0, v1, v2, v3};
        *(float4*)&outf[(size_t)row * N + col0] = o;
      }
    }
  }
}

// ---------------- flash attention, KVBLK=128 ----------------
// grid 512: id -> bh = id>>4, qt = 15-(id&15). 4 waves, wave w: q rows qt*64+w*16..+15.
// K [128][64] and V^T [64][128] staged via gload_lds16 with XOR slot swizzle.
// S^T = mfma(K,Q): lane lr = q-row (softmax state lane-local).
// PV = mfma(V^T,P): yacc also q=lr -> zero-shuffle rescale and epilogue.
__global__ __launch_bounds__(256) void k_attn(const unsigned short* __restrict__ gq,
                                              const unsigned short* __restrict__ gk,
                                              const unsigned short* __restrict__ gvt,
                                              unsigned short* __restrict__ y) {
  __shared__ unsigned short Ks[128 * 64];
  __shared__ unsigned short Vt[64 * 128];
  __shared__ unsigned short Pw[4][16 * 136];
  int id = xcd_swizzle(blockIdx.x, gridDim.x);
  int bh = id >> 4, qt = 15 - (id & 15);
  int tid = threadIdx.x, wid = tid >> 6, lane = tid & 63;
  int lr = lane & 15, lg = lane >> 4;
  int q0 = qt * 64 + wid * 16;
  int qg = q0 + lr;

  sx8 qf[2];
  {
    const unsigned short* qp = gq + ((size_t)bh * T_SEQ + qg) * DH + lg * 8;
    qf[0] = *(const sx8*)qp;
    qf[1] = *(const sx8*)(qp + 32);
  }

  fx4 yacc[4] = {};
  float mrun = -1e30f, lrun = 0.f;   // lane-local: q-row = lr

  int jmax = qt >> 1;
  for (int j = 0; j <= jmax; ++j) {
    int kt0 = j * 128;
    __syncthreads();
#pragma unroll
    for (int i = 0; i < 4; ++i) {
      int chunk = i * 256 + tid;
      {  // K tile: 128 rows x 64 elems, 8 slots/row
        int r = chunk >> 3, s = chunk & 7;
        gload_lds16(&gk[((size_t)bh * T_SEQ + kt0 + r) * DH + ((s ^ (r & 7)) << 3)],
                    &Ks[chunk << 3]);
      }
      {  // V^T tile: 64 rows x 128 elems, 16 slots/row
        int r = chunk >> 4, s = chunk & 15;
        gload_lds16(&gvt[((size_t)bh * DH + r) * T_SEQ + kt0 + ((s ^ (r & 15)) << 3)],
                    &Vt[chunk << 3]);
      }
    }
    __syncthreads();

    // S^T = K Q^T : st[mi] -> key rows mi*16+lg*4+reg, q col = lr
    fx4 st[8] = {};
#pragma unroll
    for (int kk = 0; kk < 2; ++kk) {
      int slotz = (kk * 4 + lg) ^ (lr & 7);
#pragma unroll
      for (int mi = 0; mi < 8; ++mi) {
        sx8 kb = *(const sx8*)&Ks[(mi * 16 + lr) * 64 + slotz * 8];
        st[mi] = __builtin_amdgcn_mfma_f32_16x16x32_bf16(kb, qf[kk], st[mi], 0, 0, 0);
      }
    }

    // lane-local softmax over 32 values (q = lr), reduce across 4 lg groups
    float pvv[8][4];
    float pmax = -1e30f;
    bool lastj = (j == jmax);
#pragma unroll
    for (int mi = 0; mi < 8; ++mi)
#pragma unroll
      for (int rg = 0; rg < 4; ++rg) {
        float val = st[mi][rg] * 0.125f;
        if (lastj && (kt0 + mi * 16 + lg * 4 + rg) > qg) val = -1e30f;
        pvv[mi][rg] = val;
        pmax = fmaxf(pmax, val);
      }
    pmax = fmaxf(pmax, __shfl_xor(pmax, 16));
    pmax = fmaxf(pmax, __shfl_xor(pmax, 32));
    float mnew = fmaxf(mrun, pmax);
    float sc = __expf(mrun - mnew);
    mrun = mnew;
    float ps = 0.f;
#pragma unroll
    for (int mi = 0; mi < 8; ++mi)
#pragma unroll
      for (int rg = 0; rg < 4; ++rg) {
        float e = __expf(pvv[mi][rg] - mnew);
        pvv[mi][rg] = e;
        ps += e;
      }
    ps += __shfl_xor(ps, 16);
    ps += __shfl_xor(ps, 32);
    lrun = lrun * sc + ps;

    // rescale yacc (all lane-local, q = lr)
#pragma unroll
    for (int dt = 0; dt < 4; ++dt)
#pragma unroll
      for (int rg = 0; rg < 4; ++rg) yacc[dt][rg] *= sc;

    // P -> per-wave LDS (rows q=lr, 136-elem pad), packed b32
#pragma unroll
    for (int mi = 0; mi < 8; ++mi)
#pragma unroll
      for (int rp = 0; rp < 2; ++rp) {
        unsigned pk = (unsigned)f2bf(pvv[mi][rp * 2]) |
                      ((unsigned)f2bf(pvv[mi][rp * 2 + 1]) << 16);
        *(unsigned*)&Pw[wid][lr * 136 + mi * 16 + lg * 4 + rp * 2] = pk;
      }

    // PV: yacc[dt] (q=lr rows, d cols at lg*4+reg)
#pragma unroll
    for (int kk = 0; kk < 4; ++kk) {
      sx8 pa = *(const sx8*)&Pw[wid][lr * 136 + kk * 32 + lg * 8];
      int slotz = (kk * 4 + lg) ^ lr;
#pragma unroll
      for (int dt = 0; dt < 4; ++dt) {
        sx8 vb = *(const sx8*)&Vt[(dt * 16 + lr) * 128 + slotz * 8];
        yacc[dt] = __builtin_amdgcn_mfma_f32_16x16x32_bf16(vb, pa, yacc[dt], 0, 0, 0);
      }
    }
  }

  // epilogue: y[tok][h*64 + d], all lane-local, packed 8B stores
  float inv = 1.0f / lrun;
  int tok = (bh >> 4) * T_SEQ + qg;
  int colbase = (bh & 15) * DH;
#pragma unroll
  for (int dt = 0; dt < 4; ++dt) {
    usx4 o;
#pragma unroll
    for (int rg = 0; rg < 4; ++rg) o[rg] = f2bf(yacc[dt][rg] * inv);
    *(usx4*)&y[(size_t)tok * DM + colbase + dt * 16 + lg * 4] = o;
  }
}

// ---------------- launcher ----------------
extern "C" void kernel_launch(void* const* d_in, const int* in_sizes, int n_in,
                              void* d_out, int out_size, void* d_ws, size_t ws_size,
                              hipStream_t stream) {
  (void)in_sizes; (void)n_in; (void)out_size; (void)ws_size;
  const int*   idx     = (const int*)d_in[0];
  const float* tok_emb = (const float*)d_in[1];
  const float* pos_emb = (const float*)d_in[2];
  const float* ln1_s   = (const float*)d_in[3];
  const float* ln1_b   = (const float*)d_in[4];
  const float* qkv_w   = (const float*)d_in[5];
  const float* qkv_b   = (const float*)d_in[6];
  const float* out_w   = (const float*)d_in[7];
  const float* out_b   = (const float*)d_in[8];
  const float* ln2_s   = (const float*)d_in[9];
  const float* ln2_b   = (const float*)d_in[10];
  const float* mlp_w1  = (const float*)d_in[11];
  const float* mlp_b1  = (const float*)d_in[12];
  const float* mlp_w2  = (const float*)d_in[13];
  const float* mlp_b2  = (const float*)d_in[14];
  const float* lnf_s   = (const float*)d_in[15];
  const float* lnf_b   = (const float*)d_in[16];
  const float* head_w  = (const float*)d_in[17];

  // workspace layout (~108 MB)
  char* p = (char*)d_ws;
  float* x          = (float*)p;          p += (size_t)NTOK * DM * 4;   // 8 MB
  unsigned short* h = (unsigned short*)p; p += (size_t)NTOK * DM * 2;   // 4 MB
  unsigned short* qkvb = (unsigned short*)p; p += (size_t)3 * NTOK * DM * 2; // 12 MB (q,k,v^T)
  unsigned short* yb = (unsigned short*)p; p += (size_t)NTOK * DM * 2;  // 4 MB
  unsigned short* m1 = (unsigned short*)p; p += (size_t)NTOK * DFF * 2; // 16 MB
  unsigned short* wt = (unsigned short*)p;                              // 64 MB (head)
  float* part = (float*)(p + 32 * 1024 * 1024);  // 32 MB, overlaps wt tail (layer wt use <= 8 MB)

  dim3 blk(256);

  k_embed<<<NTOK, blk, 0, stream>>>(idx, tok_emb, pos_emb, x);
  k_ln<<<NTOK, blk, 0, stream>>>(x, ln1_s, ln1_b, h);

  for (int l = 0; l < NL; ++l) {
    k_wtrans<<<dim3(DM / 64, 3 * DM / 64), blk, 0, stream>>>(qkv_w + (size_t)l * DM * 3 * DM, wt, DM, 3 * DM);
    k_gemm<0><<<16 * 24, blk, 0, stream>>>(h, wt, qkv_b + l * 3 * DM,
                                           nullptr, qkvb, nullptr, 3 * DM, DM, 24, 1);
    k_attn<<<512, blk, 0, stream>>>(qkvb, qkvb + (size_t)NTOK * DM,
                                    qkvb + (size_t)2 * NTOK * DM, yb);
    k_wtrans<<<dim3(DM / 64, DM / 64), blk, 0, stream>>>(out_w + (size_t)l * DM * DM, wt, DM, DM);
    k_gemm<2><<<16 * 8 * 4, blk, 0, stream>>>(yb, wt, out_b + l * DM,
                                              part, nullptr, nullptr, DM, DM, 8, 4);
    k_reduce_ln<<<NTOK, blk, 0, stream>>>(part, x, ln2_s + l * DM, ln2_b + l * DM, h);
    k_wtrans<<<dim3(DM / 64, DFF / 64), blk, 0, stream>>>(mlp_w1 + (size_t)l * DM * DFF, wt, DM, DFF);
    k_gemm<1><<<16 * 32, blk, 0, stream>>>(h, wt, mlp_b1 + l * DFF,
                                           nullptr, m1, nullptr, DFF, DM, 32, 1);
    k_wtrans<<<dim3(DFF / 64, DM / 64), blk, 0, stream>>>(mlp_w2 + (size_t)l * DFF * DM, wt, DFF, DM);
    k_gemm<2><<<16 * 8 * 4, blk, 0, stream>>>(m1, wt, mlp_b2 + l * DM,
                                              part, nullptr, nullptr, DM, DFF, 8, 4);
    if (l < NL - 1)
      k_reduce_ln<<<NTOK, blk, 0, stream>>>(part, x, ln1_s + (l + 1) * DM, ln1_b + (l + 1) * DM, h);
    else
      k_reduce_ln<<<NTOK, blk, 0, stream>>>(part, x, lnf_s, lnf_b, h);
  }

  k_wtrans<<<dim3(DM / 64, VOCAB / 64), blk, 0, stream>>>(head_w, wt, DM, VOCAB);
  k_gemm<3><<<16 * 250, blk, 0, stream>>>(h, wt, nullptr,
                                          nullptr, nullptr, (float*)d_out, VOCAB, DM, 250, 1);
}

// Round 4
// 1216.802 us; speedup vs baseline: 1.4371x; 1.0884x over previous
//
#include <hip/hip_runtime.h>

// GPT2-like forward, MI355X. Round 4:
// - head GEMM: 256x256 8-phase counted-vmcnt schedule (T1+T2+T3+T4+T5)
// - layer GEMMs: m97 128x128 structure (unchanged, proven)
// - attention: KVBLK=128, pre-transposed V, lane-local softmax + defer-max

#define T_SEQ 1024
#define NTOK  2048   // B*T
#define DM    1024
#define DFF   4096
#define NH    16
#define DH    64
#define NL    6
#define VOCAB 32000

typedef short sx8 __attribute__((ext_vector_type(8)));          // 8 bf16 (4 VGPR) MFMA frag
typedef float fx4 __attribute__((ext_vector_type(4)));          // MFMA acc
typedef unsigned short usx4 __attribute__((ext_vector_type(4)));
typedef unsigned int   uix4 __attribute__((ext_vector_type(4))); // 16B copy

__device__ __forceinline__ unsigned short f2bf(float f) {
  union { float f; unsigned u; } c; c.f = f;
  unsigned r = c.u + 0x7FFFu + ((c.u >> 16) & 1u);   // round-nearest-even
  return (unsigned short)(r >> 16);
}

__device__ __forceinline__ void gload_lds16(const unsigned short* g, unsigned short* l) {
  __builtin_amdgcn_global_load_lds(
      (const __attribute__((address_space(1))) unsigned int*)g,
      (__attribute__((address_space(3))) unsigned int*)l, 16, 0, 0);
}

// bijective XCD-chunked swizzle (m204)
__device__ __forceinline__ int xcd_swizzle(int orig, int nwg) {
  int q = nwg >> 3, r = nwg & 7;
  int xcd = orig & 7, idx = orig >> 3;
  int base = (xcd < r) ? xcd * (q + 1) : r * (q + 1) + (xcd - r) * q;
  return base + idx;
}

// ---------------- embedding ----------------
__global__ __launch_bounds__(256) void k_embed(const int* __restrict__ idx,
                                               const float* __restrict__ tok,
                                               const float* __restrict__ pos,
                                               float* __restrict__ x) {
  int token = blockIdx.x;
  int t = token & (T_SEQ - 1);
  int id = idx[token];
  int c = threadIdx.x * 4;
  float4 tv = *(const float4*)&tok[(size_t)id * DM + c];
  float4 pv = *(const float4*)&pos[(size_t)t * DM + c];
  float4 r;
  r.x = tv.x + pv.x; r.y = tv.y + pv.y; r.z = tv.z + pv.z; r.w = tv.w + pv.w;
  *(float4*)&x[(size_t)token * DM + c] = r;
}

// ---------------- layernorm (standalone, layer-0 ln1 only) ----------------
__global__ __launch_bounds__(256) void k_ln(const float* __restrict__ x,
                                            const float* __restrict__ g,
                                            const float* __restrict__ b,
                                            unsigned short* __restrict__ h) {
  int row = blockIdx.x;
  int tid = threadIdx.x;
  float4 v = *(const float4*)&x[(size_t)row * DM + tid * 4];
  float s = v.x + v.y + v.z + v.w;
  float q = v.x * v.x + v.y * v.y + v.z * v.z + v.w * v.w;
  for (int off = 32; off > 0; off >>= 1) {
    s += __shfl_down(s, off);
    q += __shfl_down(q, off);
  }
  __shared__ float red[8];
  int wid = tid >> 6, lane = tid & 63;
  if (lane == 0) { red[wid] = s; red[4 + wid] = q; }
  __syncthreads();
  s = red[0] + red[1] + red[2] + red[3];
  q = red[4] + red[5] + red[6] + red[7];
  float mu = s * (1.0f / DM);
  float var = q * (1.0f / DM) - mu * mu;
  float rstd = rsqrtf(var + 1e-5f);
  float4 gg = *(const float4*)&g[tid * 4];
  float4 bb = *(const float4*)&b[tid * 4];
  usx4 o;
  o[0] = f2bf((v.x - mu) * rstd * gg.x + bb.x);
  o[1] = f2bf((v.y - mu) * rstd * gg.y + bb.y);
  o[2] = f2bf((v.z - mu) * rstd * gg.z + bb.z);
  o[3] = f2bf((v.w - mu) * rstd * gg.w + bb.w);
  *(usx4*)&h[(size_t)row * DM + tid * 4] = o;
}

// ------------- fused split-K reduce + residual + layernorm -------------
__global__ __launch_bounds__(256) void k_reduce_ln(const float* __restrict__ part,
                                                   float* __restrict__ x,
                                                   const float* __restrict__ g,
                                                   const float* __restrict__ b,
                                                   unsigned short* __restrict__ h) {
  int row = blockIdx.x;
  int tid = threadIdx.x;
  int c = tid * 4;
  float4 v = *(const float4*)&x[(size_t)row * DM + c];
#pragma unroll
  for (int s4 = 0; s4 < 4; ++s4) {
    float4 p = *(const float4*)&part[((size_t)s4 * NTOK + row) * DM + c];
    v.x += p.x; v.y += p.y; v.z += p.z; v.w += p.w;
  }
  *(float4*)&x[(size_t)row * DM + c] = v;
  float s = v.x + v.y + v.z + v.w;
  float q = v.x * v.x + v.y * v.y + v.z * v.z + v.w * v.w;
  for (int off = 32; off > 0; off >>= 1) {
    s += __shfl_down(s, off);
    q += __shfl_down(q, off);
  }
  __shared__ float red[8];
  int wid = tid >> 6, lane = tid & 63;
  if (lane == 0) { red[wid] = s; red[4 + wid] = q; }
  __syncthreads();
  s = red[0] + red[1] + red[2] + red[3];
  q = red[4] + red[5] + red[6] + red[7];
  float mu = s * (1.0f / DM);
  float var = q * (1.0f / DM) - mu * mu;
  float rstd = rsqrtf(var + 1e-5f);
  float4 gg = *(const float4*)&g[c];
  float4 bb = *(const float4*)&b[c];
  usx4 o;
  o[0] = f2bf((v.x - mu) * rstd * gg.x + bb.x);
  o[1] = f2bf((v.y - mu) * rstd * gg.y + bb.y);
  o[2] = f2bf((v.z - mu) * rstd * gg.z + bb.z);
  o[3] = f2bf((v.w - mu) * rstd * gg.w + bb.w);
  *(usx4*)&h[(size_t)row * DM + c] = o;
}

// ---------------- weight convert+transpose: WT[n][k] = bf16(W[k][n]) ----------------
__global__ __launch_bounds__(256) void k_wtrans(const float* __restrict__ W,
                                                unsigned short* __restrict__ WT,
                                                int K, int N) {
  __shared__ float t[64][68];
  int k0 = blockIdx.x * 64, n0 = blockIdx.y * 64;
  int tid = threadIdx.x;
#pragma unroll
  for (int i = 0; i < 4; ++i) {
    int chunk = i * 256 + tid;
    int r = chunk >> 4, c = (chunk & 15) << 2;
    float4 v = *(const float4*)&W[(size_t)(k0 + r) * N + n0 + c];
    t[r][c] = v.x; t[r][c + 1] = v.y; t[r][c + 2] = v.z; t[r][c + 3] = v.w;
  }
  __syncthreads();
#pragma unroll
  for (int i = 0; i < 4; ++i) {
    int chunk = i * 256 + tid;
    int n = chunk >> 4, c = (chunk & 15) << 2;
    usx4 o;
    o[0] = f2bf(t[c][n]);
    o[1] = f2bf(t[c + 1][n]);
    o[2] = f2bf(t[c + 2][n]);
    o[3] = f2bf(t[c + 3][n]);
    *(usx4*)&WT[(size_t)(n0 + n) * K + k0 + c] = o;
  }
}

// ---------------- 128x128 GEMM (m97 structure) for layer GEMMs ----------------
// EPI: 0=qkv scatter(+bias, V transposed), 1=gelu(+bias)->bf16, 2=+bias -> f32 partials
template <int EPI>
__global__ __launch_bounds__(256) void k_gemm(const unsigned short* __restrict__ A,
                                              const unsigned short* __restrict__ BT,
                                              const float* __restrict__ bias,
                                              float* __restrict__ part,
                                              unsigned short* __restrict__ outb,
                                              float* __restrict__ outf,
                                              int N, int K, int NT, int KS) {
  __shared__ unsigned short As[128 * 64];
  __shared__ unsigned short Bs[128 * 64];
  int tid = threadIdx.x;
  int wid = tid >> 6, lane = tid & 63;
  int lr = lane & 15, lg = lane >> 4;

  int id = xcd_swizzle(blockIdx.x, gridDim.x);
  int mt = id & 15;
  int rest = id >> 4;
  int nt = rest % NT;
  int ks = rest / NT;
  int m0 = mt * 128, n0 = nt * 128;
  int Kslice = K / KS;
  int kbeg = ks * Kslice, kend = kbeg + Kslice;

  int wm = (wid >> 1) * 64, wn = (wid & 1) * 64;

  fx4 acc[4][4] = {};

  for (int kt = kbeg; kt < kend; kt += 64) {
    __syncthreads();
#pragma unroll
    for (int i = 0; i < 4; ++i) {
      int chunk = i * 256 + tid;
      int r = chunk >> 3;
      int slot = chunk & 7;
      int c = ((slot ^ (r & 7)) << 3);
      gload_lds16(&A[(size_t)(m0 + r) * K + kt + c], &As[chunk << 3]);
      gload_lds16(&BT[(size_t)(n0 + r) * K + kt + c], &Bs[chunk << 3]);
    }
    __syncthreads();
#pragma unroll
    for (int kk = 0; kk < 2; ++kk) {
      int slotz = (kk * 4 + lg) ^ (lr & 7);
      sx8 fa[4], fb[4];
#pragma unroll
      for (int mi = 0; mi < 4; ++mi)
        fa[mi] = *(const sx8*)&As[(wm + mi * 16 + lr) * 64 + slotz * 8];
#pragma unroll
      for (int ni = 0; ni < 4; ++ni)
        fb[ni] = *(const sx8*)&Bs[(wn + ni * 16 + lr) * 64 + slotz * 8];
#pragma unroll
      for (int mi = 0; mi < 4; ++mi)
#pragma unroll
        for (int ni = 0; ni < 4; ++ni)
          acc[mi][ni] = __builtin_amdgcn_mfma_f32_16x16x32_bf16(fb[ni], fa[mi], acc[mi][ni], 0, 0, 0);
    }
  }

#pragma unroll
  for (int ni = 0; ni < 4; ++ni) {
    int col0 = n0 + wn + ni * 16 + lg * 4;
    float4 bv = {0.f, 0.f, 0.f, 0.f};
    if (bias && ks == 0) bv = *(const float4*)&bias[col0];
#pragma unroll
    for (int mi = 0; mi < 4; ++mi) {
      int row = m0 + wm + mi * 16 + lr;
      float v0 = acc[mi][ni][0] + bv.x;
      float v1 = acc[mi][ni][1] + bv.y;
      float v2 = acc[mi][ni][2] + bv.z;
      float v3 = acc[mi][ni][3] + bv.w;
      if constexpr (EPI == 0) {
        int bb = row >> 10, tt = row & 1023;
        if (col0 < 2048) {
          int which = col0 >> 10;
          int hc = col0 & 1023;
          usx4 o = {f2bf(v0), f2bf(v1), f2bf(v2), f2bf(v3)};
          *(usx4*)&outb[(size_t)which * NTOK * DM +
                        (((size_t)bb * NH + (hc >> 6)) * T_SEQ + tt) * DH + (hc & 63)] = o;
        } else {
          int dc = col0 - 2048;
          unsigned short* vt = outb + (size_t)2 * NTOK * DM;
          size_t base = (((size_t)bb * NH + (dc >> 6)) * DH + (dc & 63)) * T_SEQ + tt;
          vt[base] = f2bf(v0);
          vt[base + T_SEQ] = f2bf(v1);
          vt[base + 2 * T_SEQ] = f2bf(v2);
          vt[base + 3 * T_SEQ] = f2bf(v3);
        }
      } else if constexpr (EPI == 1) {
        usx4 o;
        o[0] = f2bf(0.5f * v0 * (1.0f + erff(v0 * 0.70710678f)));
        o[1] = f2bf(0.5f * v1 * (1.0f + erff(v1 * 0.70710678f)));
        o[2] = f2bf(0.5f * v2 * (1.0f + erff(v2 * 0.70710678f)));
        o[3] = f2bf(0.5f * v3 * (1.0f + erff(v3 * 0.70710678f)));
        *(usx4*)&outb[(size_t)row * N + col0] = o;
      } else {
        float4 o = {v0, v1, v2, v3};
        *(float4*)&part[((size_t)ks * NTOK + row) * DM + col0] = o;
      }
    }
  }
}

// ---------------- 256x256 8-phase GEMM (head): C[M,N] f32 = A[M,K] * BT[N,K]^T ----------------
// 8 waves (2Mx4N), per-wave 128x64 out. LDS: 2buf x {A,B} x {kk0,kk1} sub-tiles [256][32].
// Per phase: ds_read frags + stage 1 half-tile + barrier + lgkmcnt(0) + 16 MFMA + barrier.
// vmcnt(6) at phases 4,8 (3 half-tiles in flight); vmcnt(0) last iteration.
#define LDSUB(buf, ab, kk) (lds + (((buf) * 2 + (ab)) * 2 + (kk)) * 8192)

__device__ __forceinline__ void stage_half(const unsigned short* g, int rowstride,
                                           unsigned short* ldsbase, int tid, int k0) {
#pragma unroll
  for (int r = 0; r < 2; ++r) {
    int chunk = r * 512 + tid;
    int row = chunk >> 2, slot = chunk & 3;
    gload_lds16(g + (size_t)row * rowstride + k0 + ((slot ^ (row & 3)) << 3),
                ldsbase + (chunk << 3));
  }
}

__global__ __launch_bounds__(512, 2) void k_gemm256(const unsigned short* __restrict__ A,
                                                    const unsigned short* __restrict__ BT,
                                                    float* __restrict__ outf,
                                                    int N, int K) {
  __shared__ unsigned short lds[8 * 8192];   // 128 KB
  int tid = threadIdx.x;
  int wid = tid >> 6, lane = tid & 63;
  int lr = lane & 15, lg = lane >> 4;
  int wm2 = wid >> 2, wn4 = wid & 3;
  int id = xcd_swizzle(blockIdx.x, gridDim.x);
  int mt = id & 7, nt = id >> 3;          // mt fastest: 8 blocks share B panel
  int m0 = mt * 256, n0 = nt * 256;
  const unsigned short* Ab = A + (size_t)m0 * K;
  const unsigned short* Bb = BT + (size_t)n0 * K;
  int NIT = K >> 7;                        // 2 K-tiles (of 64) per iteration
  int swz = (lg ^ (lr & 3)) << 3;

  fx4 acc[8][4] = {};

  // prologue: tile0 {A0,B0,A1,B1}, tile1 {A0,B0,A1} = 7 half-tiles (14 loads)
  stage_half(Ab, K, LDSUB(0, 0, 0), tid, 0);
  stage_half(Bb, K, LDSUB(0, 1, 0), tid, 0);
  stage_half(Ab, K, LDSUB(0, 0, 1), tid, 32);
  stage_half(Bb, K, LDSUB(0, 1, 1), tid, 32);
  stage_half(Ab, K, LDSUB(1, 0, 0), tid, 64);
  stage_half(Bb, K, LDSUB(1, 1, 0), tid, 64);
  stage_half(Ab, K, LDSUB(1, 0, 1), tid, 96);
  asm volatile("s_waitcnt vmcnt(6)" ::: "memory");   // tile0 fully staged
  __builtin_amdgcn_s_barrier();

#define PHASE(BUF, KK, NH, LOADA, STG, VMW)                                          \
  {                                                                                  \
    if (LOADA) {                                                                     \
      const unsigned short* sA = LDSUB(BUF, 0, KK);                                  \
      _Pragma("unroll")                                                              \
      for (int mi = 0; mi < 8; ++mi)                                                 \
        fa[mi] = *(const sx8*)&sA[(wm2 * 128 + mi * 16 + lr) * 32 + swz];            \
    }                                                                                \
    {                                                                                \
      const unsigned short* sB = LDSUB(BUF, 1, KK);                                  \
      _Pragma("unroll")                                                              \
      for (int j = 0; j < 2; ++j)                                                    \
        fb[j] = *(const sx8*)&sB[(wn4 * 64 + (NH) * 32 + j * 16 + lr) * 32 + swz];   \
    }                                                                                \
    STG;                                                                             \
    VMW;                                                                             \
    __builtin_amdgcn_sched_barrier(0);                                               \
    __builtin_amdgcn_s_barrier();                                                    \
    asm volatile("s_waitcnt lgkmcnt(0)" ::: "memory");                               \
    __builtin_amdgcn_sched_barrier(0);                                               \
    __builtin_amdgcn_s_setprio(1);                                                   \
    _Pragma("unroll")                                                                \
    for (int mi = 0; mi < 8; ++mi) {                                                 \
      acc[mi][(NH) * 2 + 0] = __builtin_amdgcn_mfma_f32_16x16x32_bf16(               \
          fb[0], fa[mi], acc[mi][(NH) * 2 + 0], 0, 0, 0);                            \
      acc[mi][(NH) * 2 + 1] = __builtin_amdgcn_mfma_f32_16x16x32_bf16(               \
          fb[1], fa[mi], acc[mi][(NH) * 2 + 1], 0, 0, 0);                            \
    }                                                                                \
    __builtin_amdgcn_s_setprio(0);                                                   \
    __builtin_amdgcn_sched_barrier(0);                                               \
    __builtin_amdgcn_s_barrier();                                                    \
  }

  for (int it = 0; it < NIT; ++it) {
    bool st = (it < NIT - 1);
    bool last = (it == NIT - 1);
    int t1k = (2 * it + 1) * 64;      // k-base of tile t1
    int t2k = (2 * it + 2) * 64;      // tile t0+2 (buf0)
    int t3k = (2 * it + 3) * 64;      // tile t1+2 (buf1)
    sx8 fa[8], fb[2];

    // p1: buf0 kk0 nh0 | stage B_kk1(t1) -> buf1
    PHASE(0, 0, 0, true,
          { stage_half(Bb, K, LDSUB(1, 1, 1), tid, t1k + 32); }, {});
    // p2: buf0 kk0 nh1 | stage A_kk0(t0+2) -> buf0
    PHASE(0, 0, 1, false,
          { if (st) stage_half(Ab, K, LDSUB(0, 0, 0), tid, t2k); }, {});
    // p3: buf0 kk1 nh0 | stage B_kk0(t0+2)
    PHASE(0, 1, 0, true,
          { if (st) stage_half(Bb, K, LDSUB(0, 1, 0), tid, t2k); }, {});
    // p4: buf0 kk1 nh1 | stage A_kk1(t0+2) | vmcnt: tile t1 confirmed
    PHASE(0, 1, 1, false,
          { if (st) stage_half(Ab, K, LDSUB(0, 0, 1), tid, t2k + 32); },
          { if (last) { asm volatile("s_waitcnt vmcnt(0)" ::: "memory"); }
            else      { asm volatile("s_waitcnt vmcnt(6)" ::: "memory"); } });
    // p5: buf1 kk0 nh0 | stage B_kk1(t0+2)
    PHASE(1, 0, 0, true,
          { if (st) stage_half(Bb, K, LDSUB(0, 1, 1), tid, t2k + 32); }, {});
    // p6: buf1 kk0 nh1 | stage A_kk0(t1+2) -> buf1
    PHASE(1, 0, 1, false,
          { if (st) stage_half(Ab, K, LDSUB(1, 0, 0), tid, t3k); }, {});
    // p7: buf1 kk1 nh0 | stage B_kk0(t1+2)
    PHASE(1, 1, 0, true,
          { if (st) stage_half(Bb, K, LDSUB(1, 1, 0), tid, t3k); }, {});
    // p8: buf1 kk1 nh1 | stage A_kk1(t1+2) | vmcnt: tile t0+2 confirmed
    PHASE(1, 1, 1, false,
          { if (st) stage_half(Ab, K, LDSUB(1, 0, 1), tid, t3k + 32); },
          { if (!last) { asm volatile("s_waitcnt vmcnt(6)" ::: "memory"); } });
  }
#undef PHASE

  // epilogue: lane (lr,lg): row = m0+wm2*128+mi*16+lr, cols = n0+wn4*64+nj*16+lg*4
#pragma unroll
  for (int mi = 0; mi < 8; ++mi) {
    int row = m0 + wm2 * 128 + mi * 16 + lr;
    float* orow = outf + (size_t)row * N + n0 + wn4 * 64 + lg * 4;
#pragma unroll
    for (int nj = 0; nj < 4; ++nj) {
      float4 o = {acc[mi][nj][0], acc[mi][nj][1], acc[mi][nj][2], acc[mi][nj][3]};
      *(float4*)&orow[nj * 16] = o;
    }
  }
}

// ---------------- flash attention, KVBLK=128, defer-max ----------------
__global__ __launch_bounds__(256) void k_attn(const unsigned short* __restrict__ gq,
                                              const unsigned short* __restrict__ gk,
                                              const unsigned short* __restrict__ gvt,
                                              unsigned short* __restrict__ y) {
  __shared__ unsigned short Ks[128 * 64];
  __shared__ unsigned short Vt[64 * 128];
  __shared__ unsigned short Pw[4][16 * 136];
  int id = xcd_swizzle(blockIdx.x, gridDim.x);
  int bh = id >> 4, qt = 15 - (id & 15);
  int tid = threadIdx.x, wid = tid >> 6, lane = tid & 63;
  int lr = lane & 15, lg = lane >> 4;
  int q0 = qt * 64 + wid * 16;
  int qg = q0 + lr;

  sx8 qf[2];
  {
    const unsigned short* qp = gq + ((size_t)bh * T_SEQ + qg) * DH + lg * 8;
    qf[0] = *(const sx8*)qp;
    qf[1] = *(const sx8*)(qp + 32);
  }

  fx4 yacc[4] = {};
  float mrun = -1e30f, lrun = 0.f;   // lane-local: q-row = lr

  int jmax = qt >> 1;
  for (int j = 0; j <= jmax; ++j) {
    int kt0 = j * 128;
    __syncthreads();
#pragma unroll
    for (int i = 0; i < 4; ++i) {
      int chunk = i * 256 + tid;
      {
        int r = chunk >> 3, s = chunk & 7;
        gload_lds16(&gk[((size_t)bh * T_SEQ + kt0 + r) * DH + ((s ^ (r & 7)) << 3)],
                    &Ks[chunk << 3]);
      }
      {
        int r = chunk >> 4, s = chunk & 15;
        gload_lds16(&gvt[((size_t)bh * DH + r) * T_SEQ + kt0 + ((s ^ (r & 15)) << 3)],
                    &Vt[chunk << 3]);
      }
    }
    __syncthreads();

    // S^T = K Q^T
    fx4 st[8] = {};
#pragma unroll
    for (int kk = 0; kk < 2; ++kk) {
      int slotz = (kk * 4 + lg) ^ (lr & 7);
#pragma unroll
      for (int mi = 0; mi < 8; ++mi) {
        sx8 kb = *(const sx8*)&Ks[(mi * 16 + lr) * 64 + slotz * 8];
        st[mi] = __builtin_amdgcn_mfma_f32_16x16x32_bf16(kb, qf[kk], st[mi], 0, 0, 0);
      }
    }

    float pvv[8][4];
    float pmax = -1e30f;
    bool lastj = (j == jmax);
#pragma unroll
    for (int mi = 0; mi < 8; ++mi)
#pragma unroll
      for (int rg = 0; rg < 4; ++rg) {
        float val = st[mi][rg] * 0.125f;
        if (lastj && (kt0 + mi * 16 + lg * 4 + rg) > qg) val = -1e30f;
        pvv[mi][rg] = val;
        pmax = fmaxf(pmax, val);
      }
    pmax = fmaxf(pmax, __shfl_xor(pmax, 16));
    pmax = fmaxf(pmax, __shfl_xor(pmax, 32));
    // defer-max (T13): only rescale when max grew by > 8
    if (!__all(pmax <= mrun + 8.0f)) {
      float mnew = fmaxf(mrun, pmax);
      float sc = __expf(mrun - mnew);
      lrun *= sc;
#pragma unroll
      for (int dt = 0; dt < 4; ++dt)
#pragma unroll
        for (int rg = 0; rg < 4; ++rg) yacc[dt][rg] *= sc;
      mrun = mnew;
    }
    float ps = 0.f;
#pragma unroll
    for (int mi = 0; mi < 8; ++mi)
#pragma unroll
      for (int rg = 0; rg < 4; ++rg) {
        float e = __expf(pvv[mi][rg] - mrun);
        pvv[mi][rg] = e;
        ps += e;
      }
    ps += __shfl_xor(ps, 16);
    ps += __shfl_xor(ps, 32);
    lrun += ps;

#pragma unroll
    for (int mi = 0; mi < 8; ++mi)
#pragma unroll
      for (int rp = 0; rp < 2; ++rp) {
        unsigned pk = (unsigned)f2bf(pvv[mi][rp * 2]) |
                      ((unsigned)f2bf(pvv[mi][rp * 2 + 1]) << 16);
        *(unsigned*)&Pw[wid][lr * 136 + mi * 16 + lg * 4 + rp * 2] = pk;
      }

#pragma unroll
    for (int kk = 0; kk < 4; ++kk) {
      sx8 pa = *(const sx8*)&Pw[wid][lr * 136 + kk * 32 + lg * 8];
      int slotz = (kk * 4 + lg) ^ lr;
#pragma unroll
      for (int dt = 0; dt < 4; ++dt) {
        sx8 vb = *(const sx8*)&Vt[(dt * 16 + lr) * 128 + slotz * 8];
        yacc[dt] = __builtin_amdgcn_mfma_f32_16x16x32_bf16(vb, pa, yacc[dt], 0, 0, 0);
      }
    }
  }

  float inv = 1.0f / lrun;
  int tok = (bh >> 4) * T_SEQ + qg;
  int colbase = (bh & 15) * DH;
#pragma unroll
  for (int dt = 0; dt < 4; ++dt) {
    usx4 o;
#pragma unroll
    for (int rg = 0; rg < 4; ++rg) o[rg] = f2bf(yacc[dt][rg] * inv);
    *(usx4*)&y[(size_t)tok * DM + colbase + dt * 16 + lg * 4] = o;
  }
}

// ---------------- launcher ----------------
extern "C" void kernel_launch(void* const* d_in, const int* in_sizes, int n_in,
                              void* d_out, int out_size, void* d_ws, size_t ws_size,
                              hipStream_t stream) {
  (void)in_sizes; (void)n_in; (void)out_size; (void)ws_size;
  const int*   idx     = (const int*)d_in[0];
  const float* tok_emb = (const float*)d_in[1];
  const float* pos_emb = (const float*)d_in[2];
  const float* ln1_s   = (const float*)d_in[3];
  const float* ln1_b   = (const float*)d_in[4];
  const float* qkv_w   = (const float*)d_in[5];
  const float* qkv_b   = (const float*)d_in[6];
  const float* out_w   = (const float*)d_in[7];
  const float* out_b   = (const float*)d_in[8];
  const float* ln2_s   = (const float*)d_in[9];
  const float* ln2_b   = (const float*)d_in[10];
  const float* mlp_w1  = (const float*)d_in[11];
  const float* mlp_b1  = (const float*)d_in[12];
  const float* mlp_w2  = (const float*)d_in[13];
  const float* mlp_b2  = (const float*)d_in[14];
  const float* lnf_s   = (const float*)d_in[15];
  const float* lnf_b   = (const float*)d_in[16];
  const float* head_w  = (const float*)d_in[17];

  char* p = (char*)d_ws;
  float* x          = (float*)p;          p += (size_t)NTOK * DM * 4;
  unsigned short* h = (unsigned short*)p; p += (size_t)NTOK * DM * 2;
  unsigned short* qkvb = (unsigned short*)p; p += (size_t)3 * NTOK * DM * 2;
  unsigned short* yb = (unsigned short*)p; p += (size_t)NTOK * DM * 2;
  unsigned short* m1 = (unsigned short*)p; p += (size_t)NTOK * DFF * 2;
  unsigned short* wt = (unsigned short*)p;                              // 64 MB (head)
  float* part = (float*)(p + 32 * 1024 * 1024);  // overlaps wt tail (layer wt <= 8 MB)

  dim3 blk(256);

  k_embed<<<NTOK, blk, 0, stream>>>(idx, tok_emb, pos_emb, x);
  k_ln<<<NTOK, blk, 0, stream>>>(x, ln1_s, ln1_b, h);

  for (int l = 0; l < NL; ++l) {
    k_wtrans<<<dim3(DM / 64, 3 * DM / 64), blk, 0, stream>>>(qkv_w + (size_t)l * DM * 3 * DM, wt, DM, 3 * DM);
    k_gemm<0><<<16 * 24, blk, 0, stream>>>(h, wt, qkv_b + l * 3 * DM,
                                           nullptr, qkvb, nullptr, 3 * DM, DM, 24, 1);
    k_attn<<<512, blk, 0, stream>>>(qkvb, qkvb + (size_t)NTOK * DM,
                                    qkvb + (size_t)2 * NTOK * DM, yb);
    k_wtrans<<<dim3(DM / 64, DM / 64), blk, 0, stream>>>(out_w + (size_t)l * DM * DM, wt, DM, DM);
    k_gemm<2><<<16 * 8 * 4, blk, 0, stream>>>(yb, wt, out_b + l * DM,
                                              part, nullptr, nullptr, DM, DM, 8, 4);
    k_reduce_ln<<<NTOK, blk, 0, stream>>>(part, x, ln2_s + l * DM, ln2_b + l * DM, h);
    k_wtrans<<<dim3(DM / 64, DFF / 64), blk, 0, stream>>>(mlp_w1 + (size_t)l * DM * DFF, wt, DM, DFF);
    k_gemm<1><<<16 * 32, blk, 0, stream>>>(h, wt, mlp_b1 + l * DFF,
                                           nullptr, m1, nullptr, DFF, DM, 32, 1);
    k_wtrans<<<dim3(DFF / 64, DM / 64), blk, 0, stream>>>(mlp_w2 + (size_t)l * DFF * DM, wt, DFF, DM);
    k_gemm<2><<<16 * 8 * 4, blk, 0, stream>>>(m1, wt, mlp_b2 + l * DM,
                                              part, nullptr, nullptr, DM, DFF, 8, 4);
    if (l < NL - 1)
      k_reduce_ln<<<NTOK, blk, 0, stream>>>(part, x, ln1_s + (l + 1) * DM, ln1_b + (l + 1) * DM, h);
    else
      k_reduce_ln<<<NTOK, blk, 0, stream>>>(part, x, lnf_s, lnf_b, h);
  }

  k_wtrans<<<dim3(DM / 64, VOCAB / 64), blk, 0, stream>>>(head_w, wt, DM, VOCAB);
  // head: 256x256 tiles -> 8 mt x 125 nt = 1000 blocks, 512 threads
  k_gemm256<<<1000, 512, 0, stream>>>(h, wt, (float*)d_out, VOCAB, DM);
}

// Round 5
// 1181.505 us; speedup vs baseline: 1.4800x; 1.0299x over previous
//
#include <hip/hip_runtime.h>

// GPT2-like forward, MI355X. Round 5:
// - k_gemm256: fixed LDS slot swizzle (slot ^ ((row>>1)&3)) -> conflict-free
// - split-K partials carried as bf16 (halve partial traffic)
// - attention softmax in exp2 domain

#define T_SEQ 1024
#define NTOK  2048   // B*T
#define DM    1024
#define DFF   4096
#define NH    16
#define DH    64
#define NL    6
#define VOCAB 32000

typedef short sx8 __attribute__((ext_vector_type(8)));          // 8 bf16 (4 VGPR) MFMA frag
typedef float fx4 __attribute__((ext_vector_type(4)));          // MFMA acc
typedef unsigned short usx4 __attribute__((ext_vector_type(4)));
typedef unsigned int   uix4 __attribute__((ext_vector_type(4))); // 16B copy

__device__ __forceinline__ unsigned short f2bf(float f) {
  union { float f; unsigned u; } c; c.f = f;
  unsigned r = c.u + 0x7FFFu + ((c.u >> 16) & 1u);   // round-nearest-even
  return (unsigned short)(r >> 16);
}
__device__ __forceinline__ float bf2f(unsigned short u) {
  union { unsigned u; float f; } c; c.u = ((unsigned)u) << 16;
  return c.f;
}

__device__ __forceinline__ void gload_lds16(const unsigned short* g, unsigned short* l) {
  __builtin_amdgcn_global_load_lds(
      (const __attribute__((address_space(1))) unsigned int*)g,
      (__attribute__((address_space(3))) unsigned int*)l, 16, 0, 0);
}

// bijective XCD-chunked swizzle (m204)
__device__ __forceinline__ int xcd_swizzle(int orig, int nwg) {
  int q = nwg >> 3, r = nwg & 7;
  int xcd = orig & 7, idx = orig >> 3;
  int base = (xcd < r) ? xcd * (q + 1) : r * (q + 1) + (xcd - r) * q;
  return base + idx;
}

// ---------------- embedding ----------------
__global__ __launch_bounds__(256) void k_embed(const int* __restrict__ idx,
                                               const float* __restrict__ tok,
                                               const float* __restrict__ pos,
                                               float* __restrict__ x) {
  int token = blockIdx.x;
  int t = token & (T_SEQ - 1);
  int id = idx[token];
  int c = threadIdx.x * 4;
  float4 tv = *(const float4*)&tok[(size_t)id * DM + c];
  float4 pv = *(const float4*)&pos[(size_t)t * DM + c];
  float4 r;
  r.x = tv.x + pv.x; r.y = tv.y + pv.y; r.z = tv.z + pv.z; r.w = tv.w + pv.w;
  *(float4*)&x[(size_t)token * DM + c] = r;
}

// ---------------- layernorm (standalone, layer-0 ln1 only) ----------------
__global__ __launch_bounds__(256) void k_ln(const float* __restrict__ x,
                                            const float* __restrict__ g,
                                            const float* __restrict__ b,
                                            unsigned short* __restrict__ h) {
  int row = blockIdx.x;
  int tid = threadIdx.x;
  float4 v = *(const float4*)&x[(size_t)row * DM + tid * 4];
  float s = v.x + v.y + v.z + v.w;
  float q = v.x * v.x + v.y * v.y + v.z * v.z + v.w * v.w;
  for (int off = 32; off > 0; off >>= 1) {
    s += __shfl_down(s, off);
    q += __shfl_down(q, off);
  }
  __shared__ float red[8];
  int wid = tid >> 6, lane = tid & 63;
  if (lane == 0) { red[wid] = s; red[4 + wid] = q; }
  __syncthreads();
  s = red[0] + red[1] + red[2] + red[3];
  q = red[4] + red[5] + red[6] + red[7];
  float mu = s * (1.0f / DM);
  float var = q * (1.0f / DM) - mu * mu;
  float rstd = rsqrtf(var + 1e-5f);
  float4 gg = *(const float4*)&g[tid * 4];
  float4 bb = *(const float4*)&b[tid * 4];
  usx4 o;
  o[0] = f2bf((v.x - mu) * rstd * gg.x + bb.x);
  o[1] = f2bf((v.y - mu) * rstd * gg.y + bb.y);
  o[2] = f2bf((v.z - mu) * rstd * gg.z + bb.z);
  o[3] = f2bf((v.w - mu) * rstd * gg.w + bb.w);
  *(usx4*)&h[(size_t)row * DM + tid * 4] = o;
}

// ------------- fused split-K reduce (bf16 partials) + residual + layernorm -------------
__global__ __launch_bounds__(256) void k_reduce_ln(const unsigned short* __restrict__ part,
                                                   float* __restrict__ x,
                                                   const float* __restrict__ g,
                                                   const float* __restrict__ b,
                                                   unsigned short* __restrict__ h) {
  int row = blockIdx.x;
  int tid = threadIdx.x;
  int c = tid * 4;
  float4 v = *(const float4*)&x[(size_t)row * DM + c];
#pragma unroll
  for (int s4 = 0; s4 < 4; ++s4) {
    usx4 p = *(const usx4*)&part[((size_t)s4 * NTOK + row) * DM + c];
    v.x += bf2f(p[0]); v.y += bf2f(p[1]); v.z += bf2f(p[2]); v.w += bf2f(p[3]);
  }
  *(float4*)&x[(size_t)row * DM + c] = v;
  float s = v.x + v.y + v.z + v.w;
  float q = v.x * v.x + v.y * v.y + v.z * v.z + v.w * v.w;
  for (int off = 32; off > 0; off >>= 1) {
    s += __shfl_down(s, off);
    q += __shfl_down(q, off);
  }
  __shared__ float red[8];
  int wid = tid >> 6, lane = tid & 63;
  if (lane == 0) { red[wid] = s; red[4 + wid] = q; }
  __syncthreads();
  s = red[0] + red[1] + red[2] + red[3];
  q = red[4] + red[5] + red[6] + red[7];
  float mu = s * (1.0f / DM);
  float var = q * (1.0f / DM) - mu * mu;
  float rstd = rsqrtf(var + 1e-5f);
  float4 gg = *(const float4*)&g[c];
  float4 bb = *(const float4*)&b[c];
  usx4 o;
  o[0] = f2bf((v.x - mu) * rstd * gg.x + bb.x);
  o[1] = f2bf((v.y - mu) * rstd * gg.y + bb.y);
  o[2] = f2bf((v.z - mu) * rstd * gg.z + bb.z);
  o[3] = f2bf((v.w - mu) * rstd * gg.w + bb.w);
  *(usx4*)&h[(size_t)row * DM + c] = o;
}

// ---------------- weight convert+transpose: WT[n][k] = bf16(W[k][n]) ----------------
__global__ __launch_bounds__(256) void k_wtrans(const float* __restrict__ W,
                                                unsigned short* __restrict__ WT,
                                                int K, int N) {
  __shared__ float t[64][68];
  int k0 = blockIdx.x * 64, n0 = blockIdx.y * 64;
  int tid = threadIdx.x;
#pragma unroll
  for (int i = 0; i < 4; ++i) {
    int chunk = i * 256 + tid;
    int r = chunk >> 4, c = (chunk & 15) << 2;
    float4 v = *(const float4*)&W[(size_t)(k0 + r) * N + n0 + c];
    t[r][c] = v.x; t[r][c + 1] = v.y; t[r][c + 2] = v.z; t[r][c + 3] = v.w;
  }
  __syncthreads();
#pragma unroll
  for (int i = 0; i < 4; ++i) {
    int chunk = i * 256 + tid;
    int n = chunk >> 4, c = (chunk & 15) << 2;
    usx4 o;
    o[0] = f2bf(t[c][n]);
    o[1] = f2bf(t[c + 1][n]);
    o[2] = f2bf(t[c + 2][n]);
    o[3] = f2bf(t[c + 3][n]);
    *(usx4*)&WT[(size_t)(n0 + n) * K + k0 + c] = o;
  }
}

// ---------------- 128x128 GEMM (m97 structure) for layer GEMMs ----------------
// EPI: 0=qkv scatter(+bias, V transposed), 1=gelu(+bias)->bf16, 2=+bias -> bf16 partials
template <int EPI>
__global__ __launch_bounds__(256) void k_gemm(const unsigned short* __restrict__ A,
                                              const unsigned short* __restrict__ BT,
                                              const float* __restrict__ bias,
                                              unsigned short* __restrict__ part,
                                              unsigned short* __restrict__ outb,
                                              float* __restrict__ outf,
                                              int N, int K, int NT, int KS) {
  __shared__ unsigned short As[128 * 64];
  __shared__ unsigned short Bs[128 * 64];
  int tid = threadIdx.x;
  int wid = tid >> 6, lane = tid & 63;
  int lr = lane & 15, lg = lane >> 4;

  int id = xcd_swizzle(blockIdx.x, gridDim.x);
  int mt = id & 15;
  int rest = id >> 4;
  int nt = rest % NT;
  int ks = rest / NT;
  int m0 = mt * 128, n0 = nt * 128;
  int Kslice = K / KS;
  int kbeg = ks * Kslice, kend = kbeg + Kslice;

  int wm = (wid >> 1) * 64, wn = (wid & 1) * 64;

  fx4 acc[4][4] = {};

  for (int kt = kbeg; kt < kend; kt += 64) {
    __syncthreads();
#pragma unroll
    for (int i = 0; i < 4; ++i) {
      int chunk = i * 256 + tid;
      int r = chunk >> 3;
      int slot = chunk & 7;
      int c = ((slot ^ (r & 7)) << 3);
      gload_lds16(&A[(size_t)(m0 + r) * K + kt + c], &As[chunk << 3]);
      gload_lds16(&BT[(size_t)(n0 + r) * K + kt + c], &Bs[chunk << 3]);
    }
    __syncthreads();
#pragma unroll
    for (int kk = 0; kk < 2; ++kk) {
      int slotz = (kk * 4 + lg) ^ (lr & 7);
      sx8 fa[4], fb[4];
#pragma unroll
      for (int mi = 0; mi < 4; ++mi)
        fa[mi] = *(const sx8*)&As[(wm + mi * 16 + lr) * 64 + slotz * 8];
#pragma unroll
      for (int ni = 0; ni < 4; ++ni)
        fb[ni] = *(const sx8*)&Bs[(wn + ni * 16 + lr) * 64 + slotz * 8];
#pragma unroll
      for (int mi = 0; mi < 4; ++mi)
#pragma unroll
        for (int ni = 0; ni < 4; ++ni)
          acc[mi][ni] = __builtin_amdgcn_mfma_f32_16x16x32_bf16(fb[ni], fa[mi], acc[mi][ni], 0, 0, 0);
    }
  }

#pragma unroll
  for (int ni = 0; ni < 4; ++ni) {
    int col0 = n0 + wn + ni * 16 + lg * 4;
    float4 bv = {0.f, 0.f, 0.f, 0.f};
    if (bias && ks == 0) bv = *(const float4*)&bias[col0];
#pragma unroll
    for (int mi = 0; mi < 4; ++mi) {
      int row = m0 + wm + mi * 16 + lr;
      float v0 = acc[mi][ni][0] + bv.x;
      float v1 = acc[mi][ni][1] + bv.y;
      float v2 = acc[mi][ni][2] + bv.z;
      float v3 = acc[mi][ni][3] + bv.w;
      if constexpr (EPI == 0) {
        int bb = row >> 10, tt = row & 1023;
        if (col0 < 2048) {
          int which = col0 >> 10;
          int hc = col0 & 1023;
          usx4 o = {f2bf(v0), f2bf(v1), f2bf(v2), f2bf(v3)};
          *(usx4*)&outb[(size_t)which * NTOK * DM +
                        (((size_t)bb * NH + (hc >> 6)) * T_SEQ + tt) * DH + (hc & 63)] = o;
        } else {
          int dc = col0 - 2048;
          unsigned short* vt = outb + (size_t)2 * NTOK * DM;
          size_t base = (((size_t)bb * NH + (dc >> 6)) * DH + (dc & 63)) * T_SEQ + tt;
          vt[base] = f2bf(v0);
          vt[base + T_SEQ] = f2bf(v1);
          vt[base + 2 * T_SEQ] = f2bf(v2);
          vt[base + 3 * T_SEQ] = f2bf(v3);
        }
      } else if constexpr (EPI == 1) {
        usx4 o;
        o[0] = f2bf(0.5f * v0 * (1.0f + erff(v0 * 0.70710678f)));
        o[1] = f2bf(0.5f * v1 * (1.0f + erff(v1 * 0.70710678f)));
        o[2] = f2bf(0.5f * v2 * (1.0f + erff(v2 * 0.70710678f)));
        o[3] = f2bf(0.5f * v3 * (1.0f + erff(v3 * 0.70710678f)));
        *(usx4*)&outb[(size_t)row * N + col0] = o;
      } else {  // bf16 partial slice (split-K)
        usx4 o = {f2bf(v0), f2bf(v1), f2bf(v2), f2bf(v3)};
        *(usx4*)&part[((size_t)ks * NTOK + row) * DM + col0] = o;
      }
    }
  }
}

// ---------------- 256x256 8-phase GEMM (head) ----------------
// LDS subtiles [256][32] (64B rows): conflict-free slot swizzle = slot ^ ((row>>1)&3)
// (8-lane issue groups: parity(row) x 4 slots -> 8 distinct 16B windows = 32 banks).
#define LDSUB(buf, ab, kk) (lds + (((buf) * 2 + (ab)) * 2 + (kk)) * 8192)

__device__ __forceinline__ void stage_half(const unsigned short* g, int rowstride,
                                           unsigned short* ldsbase, int tid, int k0) {
#pragma unroll
  for (int r = 0; r < 2; ++r) {
    int chunk = r * 512 + tid;
    int row = chunk >> 2, slot = chunk & 3;
    gload_lds16(g + (size_t)row * rowstride + k0 + ((slot ^ ((row >> 1) & 3)) << 3),
                ldsbase + (chunk << 3));
  }
}

__global__ __launch_bounds__(512, 2) void k_gemm256(const unsigned short* __restrict__ A,
                                                    const unsigned short* __restrict__ BT,
                                                    float* __restrict__ outf,
                                                    int N, int K) {
  __shared__ unsigned short lds[8 * 8192];   // 128 KB
  int tid = threadIdx.x;
  int wid = tid >> 6, lane = tid & 63;
  int lr = lane & 15, lg = lane >> 4;
  int wm2 = wid >> 2, wn4 = wid & 3;
  int id = xcd_swizzle(blockIdx.x, gridDim.x);
  int mt = id & 7, nt = id >> 3;          // mt fastest: 8 blocks share B panel
  int m0 = mt * 256, n0 = nt * 256;
  const unsigned short* Ab = A + (size_t)m0 * K;
  const unsigned short* Bb = BT + (size_t)n0 * K;
  int NIT = K >> 7;                        // 2 K-tiles (of 64) per iteration
  int swz = (lg ^ ((lr >> 1) & 3)) << 3;   // matches stage_half swizzle

  fx4 acc[8][4] = {};

  // prologue: tile0 {A0,B0,A1,B1}, tile1 {A0,B0,A1} = 7 half-tiles (14 loads)
  stage_half(Ab, K, LDSUB(0, 0, 0), tid, 0);
  stage_half(Bb, K, LDSUB(0, 1, 0), tid, 0);
  stage_half(Ab, K, LDSUB(0, 0, 1), tid, 32);
  stage_half(Bb, K, LDSUB(0, 1, 1), tid, 32);
  stage_half(Ab, K, LDSUB(1, 0, 0), tid, 64);
  stage_half(Bb, K, LDSUB(1, 1, 0), tid, 64);
  stage_half(Ab, K, LDSUB(1, 0, 1), tid, 96);
  asm volatile("s_waitcnt vmcnt(6)" ::: "memory");   // tile0 fully staged
  __builtin_amdgcn_s_barrier();

#define PHASE(BUF, KK, NHH, LOADA, STG, VMW)                                         \
  {                                                                                  \
    if (LOADA) {                                                                     \
      const unsigned short* sA = LDSUB(BUF, 0, KK);                                  \
      _Pragma("unroll")                                                              \
      for (int mi = 0; mi < 8; ++mi)                                                 \
        fa[mi] = *(const sx8*)&sA[(wm2 * 128 + mi * 16 + lr) * 32 + swz];            \
    }                                                                                \
    {                                                                                \
      const unsigned short* sB = LDSUB(BUF, 1, KK);                                  \
      _Pragma("unroll")                                                              \
      for (int j = 0; j < 2; ++j)                                                    \
        fb[j] = *(const sx8*)&sB[(wn4 * 64 + (NHH) * 32 + j * 16 + lr) * 32 + swz];  \
    }                                                                                \
    STG;                                                                             \
    VMW;                                                                             \
    __builtin_amdgcn_sched_barrier(0);                                               \
    __builtin_amdgcn_s_barrier();                                                    \
    asm volatile("s_waitcnt lgkmcnt(0)" ::: "memory");                               \
    __builtin_amdgcn_sched_barrier(0);                                               \
    __builtin_amdgcn_s_setprio(1);                                                   \
    _Pragma("unroll")                                                                \
    for (int mi = 0; mi < 8; ++mi) {                                                 \
      acc[mi][(NHH) * 2 + 0] = __builtin_amdgcn_mfma_f32_16x16x32_bf16(              \
          fb[0], fa[mi], acc[mi][(NHH) * 2 + 0], 0, 0, 0);                           \
      acc[mi][(NHH) * 2 + 1] = __builtin_amdgcn_mfma_f32_16x16x32_bf16(              \
          fb[1], fa[mi], acc[mi][(NHH) * 2 + 1], 0, 0, 0);                           \
    }                                                                                \
    __builtin_amdgcn_s_setprio(0);                                                   \
    __builtin_amdgcn_sched_barrier(0);                                               \
    __builtin_amdgcn_s_barrier();                                                    \
  }

  for (int it = 0; it < NIT; ++it) {
    bool st = (it < NIT - 1);
    bool last = (it == NIT - 1);
    int t1k = (2 * it + 1) * 64;
    int t2k = (2 * it + 2) * 64;
    int t3k = (2 * it + 3) * 64;
    sx8 fa[8], fb[2];

    PHASE(0, 0, 0, true,
          { stage_half(Bb, K, LDSUB(1, 1, 1), tid, t1k + 32); }, {});
    PHASE(0, 0, 1, false,
          { if (st) stage_half(Ab, K, LDSUB(0, 0, 0), tid, t2k); }, {});
    PHASE(0, 1, 0, true,
          { if (st) stage_half(Bb, K, LDSUB(0, 1, 0), tid, t2k); }, {});
    PHASE(0, 1, 1, false,
          { if (st) stage_half(Ab, K, LDSUB(0, 0, 1), tid, t2k + 32); },
          { if (last) { asm volatile("s_waitcnt vmcnt(0)" ::: "memory"); }
            else      { asm volatile("s_waitcnt vmcnt(6)" ::: "memory"); } });
    PHASE(1, 0, 0, true,
          { if (st) stage_half(Bb, K, LDSUB(0, 1, 1), tid, t2k + 32); }, {});
    PHASE(1, 0, 1, false,
          { if (st) stage_half(Ab, K, LDSUB(1, 0, 0), tid, t3k); }, {});
    PHASE(1, 1, 0, true,
          { if (st) stage_half(Bb, K, LDSUB(1, 1, 0), tid, t3k); }, {});
    PHASE(1, 1, 1, false,
          { if (st) stage_half(Ab, K, LDSUB(1, 0, 1), tid, t3k + 32); },
          { if (!last) { asm volatile("s_waitcnt vmcnt(6)" ::: "memory"); } });
  }
#undef PHASE

#pragma unroll
  for (int mi = 0; mi < 8; ++mi) {
    int row = m0 + wm2 * 128 + mi * 16 + lr;
    float* orow = outf + (size_t)row * N + n0 + wn4 * 64 + lg * 4;
#pragma unroll
    for (int nj = 0; nj < 4; ++nj) {
      float4 o = {acc[mi][nj][0], acc[mi][nj][1], acc[mi][nj][2], acc[mi][nj][3]};
      *(float4*)&orow[nj * 16] = o;
    }
  }
}

// ---------------- flash attention, KVBLK=128, exp2-domain softmax ----------------
__global__ __launch_bounds__(256) void k_attn(const unsigned short* __restrict__ gq,
                                              const unsigned short* __restrict__ gk,
                                              const unsigned short* __restrict__ gvt,
                                              unsigned short* __restrict__ y) {
  __shared__ unsigned short Ks[128 * 64];
  __shared__ unsigned short Vt[64 * 128];
  __shared__ unsigned short Pw[4][16 * 136];
  int id = xcd_swizzle(blockIdx.x, gridDim.x);
  int bh = id >> 4, qt = 15 - (id & 15);
  int tid = threadIdx.x, wid = tid >> 6, lane = tid & 63;
  int lr = lane & 15, lg = lane >> 4;
  int q0 = qt * 64 + wid * 16;
  int qg = q0 + lr;
  const float SCL = 0.125f * 1.44269504f;   // 1/sqrt(64) * log2(e)

  sx8 qf[2];
  {
    const unsigned short* qp = gq + ((size_t)bh * T_SEQ + qg) * DH + lg * 8;
    qf[0] = *(const sx8*)qp;
    qf[1] = *(const sx8*)(qp + 32);
  }

  fx4 yacc[4] = {};
  float mrun = -1e30f, lrun = 0.f;   // lane-local (q-row = lr), log2 domain

  int jmax = qt >> 1;
  for (int j = 0; j <= jmax; ++j) {
    int kt0 = j * 128;
    __syncthreads();
#pragma unroll
    for (int i = 0; i < 4; ++i) {
      int chunk = i * 256 + tid;
      {
        int r = chunk >> 3, s = chunk & 7;
        gload_lds16(&gk[((size_t)bh * T_SEQ + kt0 + r) * DH + ((s ^ (r & 7)) << 3)],
                    &Ks[chunk << 3]);
      }
      {
        int r = chunk >> 4, s = chunk & 15;
        gload_lds16(&gvt[((size_t)bh * DH + r) * T_SEQ + kt0 + ((s ^ (r & 15)) << 3)],
                    &Vt[chunk << 3]);
      }
    }
    __syncthreads();

    // S^T = K Q^T
    fx4 st[8] = {};
#pragma unroll
    for (int kk = 0; kk < 2; ++kk) {
      int slotz = (kk * 4 + lg) ^ (lr & 7);
#pragma unroll
      for (int mi = 0; mi < 8; ++mi) {
        sx8 kb = *(const sx8*)&Ks[(mi * 16 + lr) * 64 + slotz * 8];
        st[mi] = __builtin_amdgcn_mfma_f32_16x16x32_bf16(kb, qf[kk], st[mi], 0, 0, 0);
      }
    }

    float pvv[8][4];
    float pmax = -1e30f;
    bool lastj = (j == jmax);
#pragma unroll
    for (int mi = 0; mi < 8; ++mi)
#pragma unroll
      for (int rg = 0; rg < 4; ++rg) {
        float val = st[mi][rg] * SCL;
        if (lastj && (kt0 + mi * 16 + lg * 4 + rg) > qg) val = -1e30f;
        pvv[mi][rg] = val;
        pmax = fmaxf(pmax, val);
      }
    pmax = fmaxf(pmax, __shfl_xor(pmax, 16));
    pmax = fmaxf(pmax, __shfl_xor(pmax, 32));
    // defer-max (T13): rescale only when max grew > 11.5 (= e^8 in log2 units)
    if (!__all(pmax <= mrun + 11.5f)) {
      float mnew = fmaxf(mrun, pmax);
      float sc = exp2f(mrun - mnew);
      lrun *= sc;
#pragma unroll
      for (int dt = 0; dt < 4; ++dt)
#pragma unroll
        for (int rg = 0; rg < 4; ++rg) yacc[dt][rg] *= sc;
      mrun = mnew;
    }
    float ps = 0.f;
#pragma unroll
    for (int mi = 0; mi < 8; ++mi)
#pragma unroll
      for (int rg = 0; rg < 4; ++rg) {
        float e = exp2f(pvv[mi][rg] - mrun);
        pvv[mi][rg] = e;
        ps += e;
      }
    ps += __shfl_xor(ps, 16);
    ps += __shfl_xor(ps, 32);
    lrun += ps;

#pragma unroll
    for (int mi = 0; mi < 8; ++mi)
#pragma unroll
      for (int rp = 0; rp < 2; ++rp) {
        unsigned pk = (unsigned)f2bf(pvv[mi][rp * 2]) |
                      ((unsigned)f2bf(pvv[mi][rp * 2 + 1]) << 16);
        *(unsigned*)&Pw[wid][lr * 136 + mi * 16 + lg * 4 + rp * 2] = pk;
      }

#pragma unroll
    for (int kk = 0; kk < 4; ++kk) {
      sx8 pa = *(const sx8*)&Pw[wid][lr * 136 + kk * 32 + lg * 8];
      int slotz = (kk * 4 + lg) ^ lr;
#pragma unroll
      for (int dt = 0; dt < 4; ++dt) {
        sx8 vb = *(const sx8*)&Vt[(dt * 16 + lr) * 128 + slotz * 8];
        yacc[dt] = __builtin_amdgcn_mfma_f32_16x16x32_bf16(vb, pa, yacc[dt], 0, 0, 0);
      }
    }
  }

  float inv = 1.0f / lrun;
  int tok = (bh >> 4) * T_SEQ + qg;
  int colbase = (bh & 15) * DH;
#pragma unroll
  for (int dt = 0; dt < 4; ++dt) {
    usx4 o;
#pragma unroll
    for (int rg = 0; rg < 4; ++rg) o[rg] = f2bf(yacc[dt][rg] * inv);
    *(usx4*)&y[(size_t)tok * DM + colbase + dt * 16 + lg * 4] = o;
  }
}

// ---------------- launcher ----------------
extern "C" void kernel_launch(void* const* d_in, const int* in_sizes, int n_in,
                              void* d_out, int out_size, void* d_ws, size_t ws_size,
                              hipStream_t stream) {
  (void)in_sizes; (void)n_in; (void)out_size; (void)ws_size;
  const int*   idx     = (const int*)d_in[0];
  const float* tok_emb = (const float*)d_in[1];
  const float* pos_emb = (const float*)d_in[2];
  const float* ln1_s   = (const float*)d_in[3];
  const float* ln1_b   = (const float*)d_in[4];
  const float* qkv_w   = (const float*)d_in[5];
  const float* qkv_b   = (const float*)d_in[6];
  const float* out_w   = (const float*)d_in[7];
  const float* out_b   = (const float*)d_in[8];
  const float* ln2_s   = (const float*)d_in[9];
  const float* ln2_b   = (const float*)d_in[10];
  const float* mlp_w1  = (const float*)d_in[11];
  const float* mlp_b1  = (const float*)d_in[12];
  const float* mlp_w2  = (const float*)d_in[13];
  const float* mlp_b2  = (const float*)d_in[14];
  const float* lnf_s   = (const float*)d_in[15];
  const float* lnf_b   = (const float*)d_in[16];
  const float* head_w  = (const float*)d_in[17];

  char* p = (char*)d_ws;
  float* x          = (float*)p;          p += (size_t)NTOK * DM * 4;
  unsigned short* h = (unsigned short*)p; p += (size_t)NTOK * DM * 2;
  unsigned short* qkvb = (unsigned short*)p; p += (size_t)3 * NTOK * DM * 2;
  unsigned short* yb = (unsigned short*)p; p += (size_t)NTOK * DM * 2;
  unsigned short* m1 = (unsigned short*)p; p += (size_t)NTOK * DFF * 2;
  unsigned short* wt = (unsigned short*)p;                              // 64 MB (head)
  unsigned short* part = (unsigned short*)(p + 32 * 1024 * 1024);  // 16 MB bf16 partials

  dim3 blk(256);

  k_embed<<<NTOK, blk, 0, stream>>>(idx, tok_emb, pos_emb, x);
  k_ln<<<NTOK, blk, 0, stream>>>(x, ln1_s, ln1_b, h);

  for (int l = 0; l < NL; ++l) {
    k_wtrans<<<dim3(DM / 64, 3 * DM / 64), blk, 0, stream>>>(qkv_w + (size_t)l * DM * 3 * DM, wt, DM, 3 * DM);
    k_gemm<0><<<16 * 24, blk, 0, stream>>>(h, wt, qkv_b + l * 3 * DM,
                                           nullptr, qkvb, nullptr, 3 * DM, DM, 24, 1);
    k_attn<<<512, blk, 0, stream>>>(qkvb, qkvb + (size_t)NTOK * DM,
                                    qkvb + (size_t)2 * NTOK * DM, yb);
    k_wtrans<<<dim3(DM / 64, DM / 64), blk, 0, stream>>>(out_w + (size_t)l * DM * DM, wt, DM, DM);
    k_gemm<2><<<16 * 8 * 4, blk, 0, stream>>>(yb, wt, out_b + l * DM,
                                              part, nullptr, nullptr, DM, DM, 8, 4);
    k_reduce_ln<<<NTOK, blk, 0, stream>>>(part, x, ln2_s + l * DM, ln2_b + l * DM, h);
    k_wtrans<<<dim3(DM / 64, DFF / 64), blk, 0, stream>>>(mlp_w1 + (size_t)l * DM * DFF, wt, DM, DFF);
    k_gemm<1><<<16 * 32, blk, 0, stream>>>(h, wt, mlp_b1 + l * DFF,
                                           nullptr, m1, nullptr, DFF, DM, 32, 1);
    k_wtrans<<<dim3(DFF / 64, DM / 64), blk, 0, stream>>>(mlp_w2 + (size_t)l * DFF * DM, wt, DFF, DM);
    k_gemm<2><<<16 * 8 * 4, blk, 0, stream>>>(m1, wt, mlp_b2 + l * DM,
                                              part, nullptr, nullptr, DM, DFF, 8, 4);
    if (l < NL - 1)
      k_reduce_ln<<<NTOK, blk, 0, stream>>>(part, x, ln1_s + (l + 1) * DM, ln1_b + (l + 1) * DM, h);
    else
      k_reduce_ln<<<NTOK, blk, 0, stream>>>(part, x, lnf_s, lnf_b, h);
  }

  k_wtrans<<<dim3(DM / 64, VOCAB / 64), blk, 0, stream>>>(head_w, wt, DM, VOCAB);
  k_gemm256<<<1000, 512, 0, stream>>>(h, wt, (float*)d_out, VOCAB, DM);
}